// Round 8
// baseline (1041.019 us; speedup 1.0000x reference)
//
#include <hip/hip_runtime.h>
#include <math.h>

// Problem constants (reference: B=2,S=1024,E=1024,H=8,D=128,L=3)
#define BDIM 2
#define SDIM 1024
#define EDIM 1024
#define HDIM 8
#define DDIM 128
#define LNUM 3
#define NZ 16
#define SCALE_F 0.08838834764831845f

// WORLD MODEL (verified R6/R7): complex64 lowered to f32 REAL-PART-ONLY.
// Output f32, out_size = B*S*E. ws >= 184 MB.
// All GEMMs: MFMA bf16x3 split precision (A=Ah+Al, B=Bh+Bl, C ~= AhBh+AhBl+AlBh).
// R8: flash-fused attention (no materialized scores), batched head projections.

typedef unsigned short u16;
typedef __attribute__((ext_vector_type(8))) short bf16x8;
typedef __attribute__((ext_vector_type(4))) float f32x4;

__device__ __forceinline__ u16 bf16_rne(float x) {
    unsigned u = __float_as_uint(x);
    u += 0x7FFFu + ((u >> 16) & 1u);
    return (u16)(u >> 16);
}
__device__ __forceinline__ float bf16f(u16 h) {
    return __uint_as_float(((unsigned)h) << 16);
}

// ---------------------------------------------------------------------------
// split f32 -> (bf16 high, bf16 low). n4 = n/4 float4 groups.
// ---------------------------------------------------------------------------
__global__ __launch_bounds__(256) void split_k(
    const float* __restrict__ in, u16* __restrict__ h, u16* __restrict__ l,
    long long n4)
{
    long long i = (long long)blockIdx.x * 256 + threadIdx.x;
    if (i >= n4) return;
    float4 v = ((const float4*)in)[i];
    float vv[4] = { v.x, v.y, v.z, v.w };
    u16 hh[4], ll[4];
#pragma unroll
    for (int j = 0; j < 4; j++) {
        hh[j] = bf16_rne(vv[j]);
        ll[j] = bf16_rne(vv[j] - bf16f(hh[j]));
    }
    ((uint2*)h)[i] = make_uint2((unsigned)hh[0] | ((unsigned)hh[1] << 16),
                                (unsigned)hh[2] | ((unsigned)hh[3] << 16));
    ((uint2*)l)[i] = make_uint2((unsigned)ll[0] | ((unsigned)ll[1] << 16),
                                (unsigned)ll[2] | ((unsigned)ll[3] << 16));
}

// ---------------------------------------------------------------------------
// MFMA bf16x3 GEMM, tile 128x128x32, 256 thr (4 waves 2x2), 4x4 16x16x32 MFMA
// tiles/wave. C[m,n] = alpha*sum_k A[m,k]*B[n,k] (+C if accum).
// 3-level batch decode: z -> zp = z/(Bdec*Hdec); r = z%(Bdec*Hdec);
// zb = r/Hdec; zh = r%Hdec.
//   aBase = aOff + zp*aSP + zb*aSB + zh*aSH
//   bBase = bOff + zp*bSP
//   cBase = cOff + zp*cSP + zb*cSB + zh*cSH
// ---------------------------------------------------------------------------
__global__ __launch_bounds__(256) void gemm3(
    const u16* __restrict__ Ah, const u16* __restrict__ Al,
    long long aOff, int lda, long long aSP, long long aSB, long long aSH,
    const u16* __restrict__ Bh, const u16* __restrict__ Bl,
    long long bOff, int ldb, long long bSP,
    u16* __restrict__ Ch, u16* __restrict__ Cl,
    long long cOff, int ldc, long long cSP, long long cSB, long long cSH,
    int Bdec, int Hdec, int K, float alpha, int accum)
{
    __shared__ __align__(16) u16 AhL[4][128][8];
    __shared__ __align__(16) u16 AlL[4][128][8];
    __shared__ __align__(16) u16 BhL[4][128][8];
    __shared__ __align__(16) u16 BlL[4][128][8];

    const int tid  = threadIdx.x;
    const int lane = tid & 63;
    const int wave = tid >> 6;
    const int quad = lane >> 4;
    const int l16  = lane & 15;
    const int z  = blockIdx.z;
    const int zp = z / (Bdec * Hdec);
    const int r  = z - zp * Bdec * Hdec;
    const int zb = r / Hdec, zh = r - zb * Hdec;
    const long long aBase = aOff + (long long)zp * aSP + (long long)zb * aSB + (long long)zh * aSH;
    const long long bBase = bOff + (long long)zp * bSP;
    const long long cBase = cOff + (long long)zp * cSP + (long long)zb * cSB + (long long)zh * cSH;
    const int bm = blockIdx.y * 128, bn = blockIdx.x * 128;
    const int wr = (wave >> 1) * 64, wc = (wave & 1) * 64;

    const int sm = tid >> 1;
    const int kh = (tid & 1) * 16;
    const int c0 = kh >> 3;

    const u16* gAh = Ah + aBase + (long long)(bm + sm) * lda + kh;
    const u16* gAl = Al + aBase + (long long)(bm + sm) * lda + kh;
    const u16* gBh = Bh + bBase + (long long)(bn + sm) * ldb + kh;
    const u16* gBl = Bl + bBase + (long long)(bn + sm) * ldb + kh;

    f32x4 acc[4][4];
#pragma unroll
    for (int i = 0; i < 4; i++)
#pragma unroll
        for (int j = 0; j < 4; j++) {
            acc[i][j][0] = 0.f; acc[i][j][1] = 0.f;
            acc[i][j][2] = 0.f; acc[i][j][3] = 0.f;
        }

    for (int k0 = 0; k0 < K; k0 += 32) {
        uint4 a0 = *(const uint4*)(gAh + k0);
        uint4 a1 = *(const uint4*)(gAh + k0 + 8);
        uint4 a2 = *(const uint4*)(gAl + k0);
        uint4 a3 = *(const uint4*)(gAl + k0 + 8);
        uint4 b0 = *(const uint4*)(gBh + k0);
        uint4 b1 = *(const uint4*)(gBh + k0 + 8);
        uint4 b2 = *(const uint4*)(gBl + k0);
        uint4 b3 = *(const uint4*)(gBl + k0 + 8);
        __syncthreads();
        *(uint4*)&AhL[c0][sm][0]     = a0;
        *(uint4*)&AhL[c0 + 1][sm][0] = a1;
        *(uint4*)&AlL[c0][sm][0]     = a2;
        *(uint4*)&AlL[c0 + 1][sm][0] = a3;
        *(uint4*)&BhL[c0][sm][0]     = b0;
        *(uint4*)&BhL[c0 + 1][sm][0] = b1;
        *(uint4*)&BlL[c0][sm][0]     = b2;
        *(uint4*)&BlL[c0 + 1][sm][0] = b3;
        __syncthreads();

        bf16x8 fah[4], fal[4], fbh[4], fbl[4];
#pragma unroll
        for (int i = 0; i < 4; i++) {
            fah[i] = *(const bf16x8*)&AhL[quad][wr + i * 16 + l16][0];
            fal[i] = *(const bf16x8*)&AlL[quad][wr + i * 16 + l16][0];
            fbh[i] = *(const bf16x8*)&BhL[quad][wc + i * 16 + l16][0];
            fbl[i] = *(const bf16x8*)&BlL[quad][wc + i * 16 + l16][0];
        }
#pragma unroll
        for (int i = 0; i < 4; i++)
#pragma unroll
            for (int j = 0; j < 4; j++) {
                acc[i][j] = __builtin_amdgcn_mfma_f32_16x16x32_bf16(fah[i], fbh[j], acc[i][j], 0, 0, 0);
                acc[i][j] = __builtin_amdgcn_mfma_f32_16x16x32_bf16(fah[i], fbl[j], acc[i][j], 0, 0, 0);
                acc[i][j] = __builtin_amdgcn_mfma_f32_16x16x32_bf16(fal[i], fbh[j], acc[i][j], 0, 0, 0);
            }
    }

#pragma unroll
    for (int i = 0; i < 4; i++)
#pragma unroll
        for (int j = 0; j < 4; j++)
#pragma unroll
            for (int rr = 0; rr < 4; rr++) {
                int m = bm + wr + i * 16 + quad * 4 + rr;
                int n = bn + wc + j * 16 + l16;
                long long ci = cBase + (long long)m * ldc + n;
                float c = acc[i][j][rr] * alpha;
                if (accum) c += bf16f(Ch[ci]) + bf16f(Cl[ci]);
                u16 hh = bf16_rne(c);
                Ch[ci] = hh;
                Cl[ci] = bf16_rne(c - bf16f(hh));
            }
}

// ---------------------------------------------------------------------------
// Flash attention: per block = one 64-row Q tile of one z = (b,h).
// O[q][d] = softmax(SCALE * Q K^T) V, online softmax over 64-col K/V tiles.
// Q/K: split [NZ][S][D] (expmapped); Vt: split [NZ][D][S]; O: split [B][S][E].
// 256 thr = 4 waves; wave w owns q-rows [w*16, w*16+16).
// ---------------------------------------------------------------------------
__global__ __launch_bounds__(256) void flash_k(
    const u16* __restrict__ Qh, const u16* __restrict__ Ql,
    const u16* __restrict__ Kh, const u16* __restrict__ Kl,
    const u16* __restrict__ Vth, const u16* __restrict__ Vtl,
    u16* __restrict__ Oh, u16* __restrict__ Ol)
{
    // union region: K tile [64][136] (8704 u16) OR V^T tile [128][72] (9216 u16)
    __shared__ __align__(16) u16 uni[2][9216];
    __shared__ __align__(16) u16 pls[2][64 * 72];

    const int tid  = threadIdx.x;
    const int lane = tid & 63;
    const int w    = tid >> 6;
    const int quad = lane >> 4;
    const int l16  = lane & 15;
    const int z    = blockIdx.z;
    const int q0   = blockIdx.x * 64;
    const long long zoff = (long long)z * SDIM * DDIM;
    const int b = z >> 3, h = z & 7;

    // Q fragments for this wave's 16 rows (row = q0 + w*16 + l16)
    const u16* qrh = Qh + zoff + (long long)(q0 + w * 16 + l16) * DDIM;
    const u16* qrl = Ql + zoff + (long long)(q0 + w * 16 + l16) * DDIM;
    bf16x8 qfh[4], qfl[4];
#pragma unroll
    for (int s = 0; s < 4; s++) {
        qfh[s] = *(const bf16x8*)(qrh + s * 32 + quad * 8);
        qfl[s] = *(const bf16x8*)(qrl + s * 32 + quad * 8);
    }

    f32x4 oacc[8];
#pragma unroll
    for (int dt = 0; dt < 8; dt++) {
        oacc[dt][0] = 0.f; oacc[dt][1] = 0.f; oacc[dt][2] = 0.f; oacc[dt][3] = 0.f;
    }
    float mold[4] = { -1e30f, -1e30f, -1e30f, -1e30f };
    float lsum[4] = { 0.f, 0.f, 0.f, 0.f };

    for (int t0 = 0; t0 < SDIM; t0 += 64) {
        // ---- stage K tile [64 t][128 d] h+l into uni ([t][136]) ----
        __syncthreads();
#pragma unroll
        for (int p = 0; p < 4; p++) {
            int idx = tid + p * 256;           // 0..1023
            int t = idx >> 4, seg = idx & 15;
            *(uint4*)&uni[0][t * 136 + seg * 8] =
                *(const uint4*)(Kh + zoff + (long long)(t0 + t) * DDIM + seg * 8);
            *(uint4*)&uni[1][t * 136 + seg * 8] =
                *(const uint4*)(Kl + zoff + (long long)(t0 + t) * DDIM + seg * 8);
        }
        __syncthreads();

        // ---- S = Q K^T (16 q x 64 t per wave), f32 accs ----
        f32x4 sacc[4];
#pragma unroll
        for (int ct = 0; ct < 4; ct++) {
            f32x4 a; a[0] = 0.f; a[1] = 0.f; a[2] = 0.f; a[3] = 0.f;
#pragma unroll
            for (int s = 0; s < 4; s++) {
                bf16x8 kbh = *(const bf16x8*)&uni[0][(ct * 16 + l16) * 136 + s * 32 + quad * 8];
                bf16x8 kbl = *(const bf16x8*)&uni[1][(ct * 16 + l16) * 136 + s * 32 + quad * 8];
                a = __builtin_amdgcn_mfma_f32_16x16x32_bf16(qfh[s], kbh, a, 0, 0, 0);
                a = __builtin_amdgcn_mfma_f32_16x16x32_bf16(qfh[s], kbl, a, 0, 0, 0);
                a = __builtin_amdgcn_mfma_f32_16x16x32_bf16(qfl[s], kbh, a, 0, 0, 0);
            }
            sacc[ct] = a;
        }

        // ---- online softmax (rows = quad*4+r, cols = ct*16+l16) ----
        float pv[4][4], alpha[4];
#pragma unroll
        for (int r = 0; r < 4; r++) {
            float mx = -1e30f;
#pragma unroll
            for (int ct = 0; ct < 4; ct++) mx = fmaxf(mx, sacc[ct][r] * SCALE_F);
#pragma unroll
            for (int msk = 1; msk < 16; msk <<= 1) mx = fmaxf(mx, __shfl_xor(mx, msk, 64));
            float mnew = fmaxf(mold[r], mx);
            alpha[r] = expf(mold[r] - mnew);
            float rs = 0.f;
#pragma unroll
            for (int ct = 0; ct < 4; ct++) {
                float p = expf(sacc[ct][r] * SCALE_F - mnew);
                pv[ct][r] = p; rs += p;
            }
#pragma unroll
            for (int msk = 1; msk < 16; msk <<= 1) rs += __shfl_xor(rs, msk, 64);
            lsum[r] = lsum[r] * alpha[r] + rs;
            mold[r] = mnew;
        }
#pragma unroll
        for (int dt = 0; dt < 8; dt++)
#pragma unroll
            for (int r = 0; r < 4; r++) oacc[dt][r] *= alpha[r];

        // ---- P (split) to LDS [64 q][72] ----
#pragma unroll
        for (int ct = 0; ct < 4; ct++)
#pragma unroll
            for (int r = 0; r < 4; r++) {
                float p = pv[ct][r];
                u16 hh = bf16_rne(p);
                int qr = w * 16 + quad * 4 + r;
                pls[0][qr * 72 + ct * 16 + l16] = hh;
                pls[1][qr * 72 + ct * 16 + l16] = bf16_rne(p - bf16f(hh));
            }
        __syncthreads();   // P visible; all waves done reading K

        // ---- stage V^T tile [128 d][64 t] h+l into uni ([d][72]) ----
#pragma unroll
        for (int p = 0; p < 4; p++) {
            int idx = tid + p * 256;           // 0..1023
            int d = idx >> 3, seg = idx & 7;
            *(uint4*)&uni[0][d * 72 + seg * 8] =
                *(const uint4*)(Vth + zoff + (long long)d * SDIM + t0 + seg * 8);
            *(uint4*)&uni[1][d * 72 + seg * 8] =
                *(const uint4*)(Vtl + zoff + (long long)d * SDIM + t0 + seg * 8);
        }
        __syncthreads();

        // ---- O += P V ----
        bf16x8 pah[2], pal[2];
#pragma unroll
        for (int ks = 0; ks < 2; ks++) {
            pah[ks] = *(const bf16x8*)&pls[0][(w * 16 + l16) * 72 + ks * 32 + quad * 8];
            pal[ks] = *(const bf16x8*)&pls[1][(w * 16 + l16) * 72 + ks * 32 + quad * 8];
        }
#pragma unroll
        for (int dt = 0; dt < 8; dt++) {
            f32x4 o = oacc[dt];
#pragma unroll
            for (int ks = 0; ks < 2; ks++) {
                bf16x8 vbh = *(const bf16x8*)&uni[0][(dt * 16 + l16) * 72 + ks * 32 + quad * 8];
                bf16x8 vbl = *(const bf16x8*)&uni[1][(dt * 16 + l16) * 72 + ks * 32 + quad * 8];
                o = __builtin_amdgcn_mfma_f32_16x16x32_bf16(pah[ks], vbh, o, 0, 0, 0);
                o = __builtin_amdgcn_mfma_f32_16x16x32_bf16(pah[ks], vbl, o, 0, 0, 0);
                o = __builtin_amdgcn_mfma_f32_16x16x32_bf16(pal[ks], vbh, o, 0, 0, 0);
            }
            oacc[dt] = o;
        }
    }

    // ---- epilogue: O /= l, write split ----
    float inv[4];
#pragma unroll
    for (int r = 0; r < 4; r++) inv[r] = 1.0f / lsum[r];
#pragma unroll
    for (int dt = 0; dt < 8; dt++)
#pragma unroll
        for (int r = 0; r < 4; r++) {
            float v = oacc[dt][r] * inv[r];
            int srow = q0 + w * 16 + quad * 4 + r;
            int d = dt * 16 + l16;
            long long idx = (long long)b * SDIM * EDIM + (long long)srow * EDIM + h * DDIM + d;
            u16 hh = bf16_rne(v);
            Oh[idx] = hh;
            Ol[idx] = bf16_rne(v - bf16f(hh));
        }
}

// ---------------------------------------------------------------------------
// expmap0 on split rows of 128: v *= tanh(|v|)/max(|v|,1e-6). One wave/row.
// ---------------------------------------------------------------------------
__global__ __launch_bounds__(64) void expmap_k(
    u16* __restrict__ qh, u16* __restrict__ ql,
    u16* __restrict__ kh, u16* __restrict__ kl)
{
    long long row = blockIdx.x;
    u16* h = (blockIdx.y == 0 ? qh : kh) + row * DDIM;
    u16* l = (blockIdx.y == 0 ? ql : kl) + row * DDIM;
    const int lane = threadIdx.x;
    float v0 = bf16f(h[lane]) + bf16f(l[lane]);
    float v1 = bf16f(h[lane + 64]) + bf16f(l[lane + 64]);
    float s = v0 * v0 + v1 * v1;
#pragma unroll
    for (int off = 32; off > 0; off >>= 1) s += __shfl_down(s, off, 64);
    s = __shfl(s, 0, 64);
    float n = fmaxf(sqrtf(s), 1e-6f);
    float scl = tanhf(n) / n;
    v0 *= scl; v1 *= scl;
    u16 hh = bf16_rne(v0);
    h[lane] = hh; l[lane] = bf16_rne(v0 - bf16f(hh));
    hh = bf16_rne(v1);
    h[lane + 64] = hh; l[lane + 64] = bf16_rne(v1 - bf16f(hh));
}

// ---------------------------------------------------------------------------
// transpose V [z][S][D] -> Vt [z][D][S] (both split). grid (S/64, D/64, NZ).
// ---------------------------------------------------------------------------
__global__ __launch_bounds__(256) void transpose_k(
    const u16* __restrict__ Vh, const u16* __restrict__ Vl,
    u16* __restrict__ Th, u16* __restrict__ Tl)
{
    __shared__ __align__(16) u16 th[64][72], tl[64][72];
    const int z = blockIdx.z;
    const int s0 = blockIdx.x * 64, d0 = blockIdx.y * 64;
    const u16* vh = Vh + (long long)z * SDIM * DDIM;
    const u16* vl = Vl + (long long)z * SDIM * DDIM;
    u16* oh = Th + (long long)z * DDIM * SDIM;
    u16* ol = Tl + (long long)z * DDIM * SDIM;
    const int t = threadIdx.x;
    const int sr = t >> 2, dc = (t & 3) * 16;
    {
        const u16* p = vh + (long long)(s0 + sr) * DDIM + d0 + dc;
        *(uint4*)&th[sr][dc]     = *(const uint4*)p;
        *(uint4*)&th[sr][dc + 8] = *(const uint4*)(p + 8);
        const u16* q = vl + (long long)(s0 + sr) * DDIM + d0 + dc;
        *(uint4*)&tl[sr][dc]     = *(const uint4*)q;
        *(uint4*)&tl[sr][dc + 8] = *(const uint4*)(q + 8);
    }
    __syncthreads();
    const int dr = t >> 2, sc = (t & 3) * 16;
    unsigned wbuf[8];
#pragma unroll
    for (int i = 0; i < 8; i++)
        wbuf[i] = (unsigned)th[sc + 2 * i][dr] | ((unsigned)th[sc + 2 * i + 1][dr] << 16);
    u16* po = oh + (long long)(d0 + dr) * SDIM + s0 + sc;
    *(uint4*)po = make_uint4(wbuf[0], wbuf[1], wbuf[2], wbuf[3]);
    *(uint4*)(po + 8) = make_uint4(wbuf[4], wbuf[5], wbuf[6], wbuf[7]);
#pragma unroll
    for (int i = 0; i < 8; i++)
        wbuf[i] = (unsigned)tl[sc + 2 * i][dr] | ((unsigned)tl[sc + 2 * i + 1][dr] << 16);
    u16* pl = ol + (long long)(d0 + dr) * SDIM + s0 + sc;
    *(uint4*)pl = make_uint4(wbuf[0], wbuf[1], wbuf[2], wbuf[3]);
    *(uint4*)(pl + 8) = make_uint4(wbuf[4], wbuf[5], wbuf[6], wbuf[7]);
}

// final output: f32 = h + l (zero-fill past nmax)
__global__ __launch_bounds__(256) void out_k(
    const u16* __restrict__ h, const u16* __restrict__ l,
    float* __restrict__ out, long long n, long long nmax)
{
    long long i = (long long)blockIdx.x * 256 + threadIdx.x;
    if (i < n) out[i] = (i < nmax) ? (bf16f(h[i]) + bf16f(l[i])) : 0.f;
}

// ---------------------------------------------------------------------------
// Workspace (u16 offsets). Total ~100 MB < 184 MB.
// ---------------------------------------------------------------------------
#define N2   2097152LL            // B*S*E == NZ*S*D
#define T1N  6291456LL            // 2048*3072
#define W3N  3145728LL            // 3E*E
#define WON  1048576LL            // E*E
#define WHN  49152LL              // 3*D*D

extern "C" void kernel_launch(void* const* d_in, const int* in_sizes, int n_in,
                              void* d_out, int out_size, void* d_ws, size_t ws_size,
                              hipStream_t stream)
{
    const float* x       = (const float*)d_in[0];
    const float* Wqkv    = (const float*)d_in[1];
    const float* Wq      = (const float*)d_in[3];
    const float* Wk      = (const float*)d_in[5];
    const float* Wv      = (const float*)d_in[7];
    const float* Wout    = (const float*)d_in[9];
    const float* Wlayers = (const float*)d_in[11];

    u16* ws = (u16*)d_ws;
    long long o = 0;
    u16 *curh = ws + o; o += N2;  u16 *curl = ws + o; o += N2;
    u16 *t1h  = ws + o; o += T1N; u16 *t1l  = ws + o; o += T1N;
    u16 *qkvh = ws + o; o += 3 * N2; u16 *qkvl = ws + o; o += 3 * N2;
    u16 *vth  = ws + o; o += N2;  u16 *vtl  = ws + o; o += N2;
    u16 *aoh  = ws + o; o += N2;  u16 *aol  = ws + o; o += N2;
    u16 *wqh  = ws + o; o += W3N; u16 *wql  = ws + o; o += W3N;
    u16 *whh  = ws + o; o += WHN; u16 *whl  = ws + o; o += WHN;
    u16 *woh  = ws + o; o += WON; u16 *wol  = ws + o; o += WON;
    u16 *wlh  = ws + o; o += W3N; u16 *wll  = ws + o; o += W3N;
    u16 *o2h = t1h, *o2l = t1h + N2;   // alias: t1 dead after head-proj

    // split inputs
    split_k<<<(unsigned)((N2 / 4 + 255) / 256), 256, 0, stream>>>(x, curh, curl, N2 / 4);
    split_k<<<(unsigned)((W3N / 4 + 255) / 256), 256, 0, stream>>>(Wqkv, wqh, wql, W3N / 4);
    split_k<<<16, 256, 0, stream>>>(Wq, whh, whl, 4096);
    split_k<<<16, 256, 0, stream>>>(Wk, whh + 16384, whl + 16384, 4096);
    split_k<<<16, 256, 0, stream>>>(Wv, whh + 32768, whl + 32768, 4096);
    split_k<<<(unsigned)((WON / 4 + 255) / 256), 256, 0, stream>>>(Wout, woh, wol, WON / 4);
    split_k<<<(unsigned)((W3N / 4 + 255) / 256), 256, 0, stream>>>(Wlayers, wlh, wll, W3N / 4);

    for (int layer = 0; layer < LNUM; layer++) {
        // t1[2048][3072] = cur @ Wqkv^T
        gemm3<<<dim3(24, 16, 1), 256, 0, stream>>>(
            curh, curl, 0, EDIM, 0, 0, 0,
            wqh, wql, 0, EDIM, 0,
            t1h, t1l, 0, 3 * EDIM, 0, 0, 0,
            1, 1, EDIM, 1.0f, 0);

        // batched head projections: z = p*16 + b*8 + h  (48 z-slices)
        gemm3<<<dim3(1, 8, 48), 256, 0, stream>>>(
            t1h, t1l, 0, 3 * EDIM,
            (long long)EDIM, (long long)SDIM * 3 * EDIM, (long long)DDIM,
            whh, whl, 0, DDIM, 16384,
            qkvh, qkvl, 0, DDIM,
            N2, (long long)HDIM * SDIM * DDIM, (long long)SDIM * DDIM,
            2, HDIM, DDIM, 1.0f, 0);

        // expmap0 on q,k
        expmap_k<<<dim3(NZ * SDIM, 2), 64, 0, stream>>>(
            qkvh, qkvl, qkvh + N2, qkvl + N2);

        // Vt[z][D][S] = V[z]^T
        transpose_k<<<dim3(16, 2, NZ), 256, 0, stream>>>(
            qkvh + 2 * N2, qkvl + 2 * N2, vth, vtl);

        // fused attention -> attnout split
        flash_k<<<dim3(16, 1, NZ), 256, 0, stream>>>(
            qkvh, qkvl, qkvh + N2, qkvl + N2, vth, vtl, aoh, aol);

        // out2 = attnout @ Wout^T
        gemm3<<<dim3(8, 16, 1), 256, 0, stream>>>(
            aoh, aol, 0, EDIM, 0, 0, 0,
            woh, wol, 0, EDIM, 0,
            o2h, o2l, 0, EDIM, 0, 0, 0,
            1, 1, EDIM, 1.0f, 0);

        // cur += out2 @ Wlayers[layer]^T
        gemm3<<<dim3(8, 16, 1), 256, 0, stream>>>(
            o2h, o2l, 0, EDIM, 0, 0, 0,
            wlh, wll, (long long)layer * EDIM * EDIM, EDIM, 0,
            curh, curl, 0, EDIM, 0, 0, 0,
            1, 1, EDIM, 1.0f, 1);
    }

    out_k<<<(out_size + 255) / 256, 256, 0, stream>>>(
        curh, curl, (float*)d_out, out_size, N2);
}

// Round 9
// 702.737 us; speedup vs baseline: 1.4814x; 1.4814x over previous
//
#include <hip/hip_runtime.h>
#include <math.h>

// Problem constants (reference: B=2,S=1024,E=1024,H=8,D=128,L=3)
#define BDIM 2
#define SDIM 1024
#define EDIM 1024
#define HDIM 8
#define DDIM 128
#define LNUM 3
#define NZ 16
#define SCALE_F 0.08838834764831845f

// WORLD MODEL (verified R6-R8): complex64 lowered to f32 REAL-PART-ONLY.
// R9: single-bf16 attention interior (error budget ~3e-4 << 0.0625 systematic),
// head-proj folded into Wqkv (Wfused, once), Wout folded into Wlayers (Wlo, once).
// cur / weight-GEMMs stay bf16x3 split precision.

typedef unsigned short u16;
typedef __attribute__((ext_vector_type(8))) short bf16x8;
typedef __attribute__((ext_vector_type(4))) float f32x4;

__device__ __forceinline__ u16 bf16_rne(float x) {
    unsigned u = __float_as_uint(x);
    u += 0x7FFFu + ((u >> 16) & 1u);
    return (u16)(u >> 16);
}
__device__ __forceinline__ float bf16f(u16 h) {
    return __uint_as_float(((unsigned)h) << 16);
}

// ---------------------------------------------------------------------------
// split f32 -> (bf16 high, bf16 low). n4 = n/4 float4 groups.
// ---------------------------------------------------------------------------
__global__ __launch_bounds__(256) void split_k(
    const float* __restrict__ in, u16* __restrict__ h, u16* __restrict__ l,
    long long n4)
{
    long long i = (long long)blockIdx.x * 256 + threadIdx.x;
    if (i >= n4) return;
    float4 v = ((const float4*)in)[i];
    float vv[4] = { v.x, v.y, v.z, v.w };
    u16 hh[4], ll[4];
#pragma unroll
    for (int j = 0; j < 4; j++) {
        hh[j] = bf16_rne(vv[j]);
        ll[j] = bf16_rne(vv[j] - bf16f(hh[j]));
    }
    ((uint2*)h)[i] = make_uint2((unsigned)hh[0] | ((unsigned)hh[1] << 16),
                                (unsigned)hh[2] | ((unsigned)hh[3] << 16));
    ((uint2*)l)[i] = make_uint2((unsigned)ll[0] | ((unsigned)ll[1] << 16),
                                (unsigned)ll[2] | ((unsigned)ll[3] << 16));
}

// ---------------------------------------------------------------------------
// MFMA bf16x3 GEMM, tile 128x128x32, 256 thr (4 waves 2x2), 4x4 16x16x32 MFMA
// tiles/wave. C[m,n] = alpha*sum_k A[m,k]*B[n,k] (+C if accum).
// 3-level batch decode: zp = z/(Bdec*Hdec); r = z%(Bdec*Hdec); zb=r/Hdec; zh=r%Hdec.
// Base = Off + zp*SP + zb*SB + zh*SH for A, B, C independently.
// ---------------------------------------------------------------------------
__global__ __launch_bounds__(256) void gemm3(
    const u16* __restrict__ Ah, const u16* __restrict__ Al,
    long long aOff, int lda, long long aSP, long long aSB, long long aSH,
    const u16* __restrict__ Bh, const u16* __restrict__ Bl,
    long long bOff, int ldb, long long bSP, long long bSB, long long bSH,
    u16* __restrict__ Ch, u16* __restrict__ Cl,
    long long cOff, int ldc, long long cSP, long long cSB, long long cSH,
    int Bdec, int Hdec, int K, float alpha, int accum)
{
    __shared__ __align__(16) u16 AhL[4][128][8];
    __shared__ __align__(16) u16 AlL[4][128][8];
    __shared__ __align__(16) u16 BhL[4][128][8];
    __shared__ __align__(16) u16 BlL[4][128][8];

    const int tid  = threadIdx.x;
    const int lane = tid & 63;
    const int wave = tid >> 6;
    const int quad = lane >> 4;
    const int l16  = lane & 15;
    const int z  = blockIdx.z;
    const int zp = z / (Bdec * Hdec);
    const int r  = z - zp * Bdec * Hdec;
    const int zb = r / Hdec, zh = r - zb * Hdec;
    const long long aBase = aOff + (long long)zp * aSP + (long long)zb * aSB + (long long)zh * aSH;
    const long long bBase = bOff + (long long)zp * bSP + (long long)zb * bSB + (long long)zh * bSH;
    const long long cBase = cOff + (long long)zp * cSP + (long long)zb * cSB + (long long)zh * cSH;
    const int bm = blockIdx.y * 128, bn = blockIdx.x * 128;
    const int wr = (wave >> 1) * 64, wc = (wave & 1) * 64;

    const int sm = tid >> 1;
    const int kh = (tid & 1) * 16;
    const int c0 = kh >> 3;

    const u16* gAh = Ah + aBase + (long long)(bm + sm) * lda + kh;
    const u16* gAl = Al + aBase + (long long)(bm + sm) * lda + kh;
    const u16* gBh = Bh + bBase + (long long)(bn + sm) * ldb + kh;
    const u16* gBl = Bl + bBase + (long long)(bn + sm) * ldb + kh;

    f32x4 acc[4][4];
#pragma unroll
    for (int i = 0; i < 4; i++)
#pragma unroll
        for (int j = 0; j < 4; j++) {
            acc[i][j][0] = 0.f; acc[i][j][1] = 0.f;
            acc[i][j][2] = 0.f; acc[i][j][3] = 0.f;
        }

    for (int k0 = 0; k0 < K; k0 += 32) {
        uint4 a0 = *(const uint4*)(gAh + k0);
        uint4 a1 = *(const uint4*)(gAh + k0 + 8);
        uint4 a2 = *(const uint4*)(gAl + k0);
        uint4 a3 = *(const uint4*)(gAl + k0 + 8);
        uint4 b0 = *(const uint4*)(gBh + k0);
        uint4 b1 = *(const uint4*)(gBh + k0 + 8);
        uint4 b2 = *(const uint4*)(gBl + k0);
        uint4 b3 = *(const uint4*)(gBl + k0 + 8);
        __syncthreads();
        *(uint4*)&AhL[c0][sm][0]     = a0;
        *(uint4*)&AhL[c0 + 1][sm][0] = a1;
        *(uint4*)&AlL[c0][sm][0]     = a2;
        *(uint4*)&AlL[c0 + 1][sm][0] = a3;
        *(uint4*)&BhL[c0][sm][0]     = b0;
        *(uint4*)&BhL[c0 + 1][sm][0] = b1;
        *(uint4*)&BlL[c0][sm][0]     = b2;
        *(uint4*)&BlL[c0 + 1][sm][0] = b3;
        __syncthreads();

        bf16x8 fah[4], fal[4], fbh[4], fbl[4];
#pragma unroll
        for (int i = 0; i < 4; i++) {
            fah[i] = *(const bf16x8*)&AhL[quad][wr + i * 16 + l16][0];
            fal[i] = *(const bf16x8*)&AlL[quad][wr + i * 16 + l16][0];
            fbh[i] = *(const bf16x8*)&BhL[quad][wc + i * 16 + l16][0];
            fbl[i] = *(const bf16x8*)&BlL[quad][wc + i * 16 + l16][0];
        }
#pragma unroll
        for (int i = 0; i < 4; i++)
#pragma unroll
            for (int j = 0; j < 4; j++) {
                acc[i][j] = __builtin_amdgcn_mfma_f32_16x16x32_bf16(fah[i], fbh[j], acc[i][j], 0, 0, 0);
                acc[i][j] = __builtin_amdgcn_mfma_f32_16x16x32_bf16(fah[i], fbl[j], acc[i][j], 0, 0, 0);
                acc[i][j] = __builtin_amdgcn_mfma_f32_16x16x32_bf16(fal[i], fbh[j], acc[i][j], 0, 0, 0);
            }
    }

#pragma unroll
    for (int i = 0; i < 4; i++)
#pragma unroll
        for (int j = 0; j < 4; j++)
#pragma unroll
            for (int rr = 0; rr < 4; rr++) {
                int m = bm + wr + i * 16 + quad * 4 + rr;
                int n = bn + wc + j * 16 + l16;
                long long ci = cBase + (long long)m * ldc + n;
                float c = acc[i][j][rr] * alpha;
                if (accum) c += bf16f(Ch[ci]) + bf16f(Cl[ci]);
                u16 hh = bf16_rne(c);
                Ch[ci] = hh;
                Cl[ci] = bf16_rne(c - bf16f(hh));
            }
}

// ---------------------------------------------------------------------------
// Flash attention, single-bf16 interior. Per block: one 64-row Q tile of one
// z=(b,h). Online softmax over 64-col K/V tiles. Output attnout split h/l.
// ---------------------------------------------------------------------------
__global__ __launch_bounds__(256) void flash_k(
    const u16* __restrict__ Qh, const u16* __restrict__ Kh,
    const u16* __restrict__ Vth,
    u16* __restrict__ Oh, u16* __restrict__ Ol)
{
    __shared__ __align__(16) u16 uni[9216];   // K tile [64][136] / V^T tile [128][72]
    __shared__ __align__(16) u16 pls[64 * 72];

    const int tid  = threadIdx.x;
    const int lane = tid & 63;
    const int w    = tid >> 6;
    const int quad = lane >> 4;
    const int l16  = lane & 15;
    const int z    = blockIdx.z;
    const int q0   = blockIdx.x * 64;
    const long long zoff = (long long)z * SDIM * DDIM;
    const int b = z >> 3, h = z & 7;

    const u16* qr = Qh + zoff + (long long)(q0 + w * 16 + l16) * DDIM;
    bf16x8 qf[4];
#pragma unroll
    for (int s = 0; s < 4; s++) qf[s] = *(const bf16x8*)(qr + s * 32 + quad * 8);

    f32x4 oacc[8];
#pragma unroll
    for (int dt = 0; dt < 8; dt++) {
        oacc[dt][0] = 0.f; oacc[dt][1] = 0.f; oacc[dt][2] = 0.f; oacc[dt][3] = 0.f;
    }
    float mold[4] = { -1e30f, -1e30f, -1e30f, -1e30f };
    float lsum[4] = { 0.f, 0.f, 0.f, 0.f };

    for (int t0 = 0; t0 < SDIM; t0 += 64) {
        __syncthreads();
#pragma unroll
        for (int p = 0; p < 4; p++) {
            int idx = tid + p * 256;           // 0..1023
            int t = idx >> 4, seg = idx & 15;
            *(uint4*)&uni[t * 136 + seg * 8] =
                *(const uint4*)(Kh + zoff + (long long)(t0 + t) * DDIM + seg * 8);
        }
        __syncthreads();

        f32x4 sacc[4];
#pragma unroll
        for (int ct = 0; ct < 4; ct++) {
            f32x4 a; a[0] = 0.f; a[1] = 0.f; a[2] = 0.f; a[3] = 0.f;
#pragma unroll
            for (int s = 0; s < 4; s++) {
                bf16x8 kb = *(const bf16x8*)&uni[(ct * 16 + l16) * 136 + s * 32 + quad * 8];
                a = __builtin_amdgcn_mfma_f32_16x16x32_bf16(qf[s], kb, a, 0, 0, 0);
            }
            sacc[ct] = a;
        }

        float pv[4][4], alpha[4];
#pragma unroll
        for (int r = 0; r < 4; r++) {
            float mx = -1e30f;
#pragma unroll
            for (int ct = 0; ct < 4; ct++) mx = fmaxf(mx, sacc[ct][r] * SCALE_F);
#pragma unroll
            for (int msk = 1; msk < 16; msk <<= 1) mx = fmaxf(mx, __shfl_xor(mx, msk, 64));
            float mnew = fmaxf(mold[r], mx);
            alpha[r] = expf(mold[r] - mnew);
            float rs = 0.f;
#pragma unroll
            for (int ct = 0; ct < 4; ct++) {
                float p = expf(sacc[ct][r] * SCALE_F - mnew);
                pv[ct][r] = p; rs += p;
            }
#pragma unroll
            for (int msk = 1; msk < 16; msk <<= 1) rs += __shfl_xor(rs, msk, 64);
            lsum[r] = lsum[r] * alpha[r] + rs;
            mold[r] = mnew;
        }
#pragma unroll
        for (int dt = 0; dt < 8; dt++)
#pragma unroll
            for (int r = 0; r < 4; r++) oacc[dt][r] *= alpha[r];

#pragma unroll
        for (int ct = 0; ct < 4; ct++)
#pragma unroll
            for (int r = 0; r < 4; r++)
                pls[(w * 16 + quad * 4 + r) * 72 + ct * 16 + l16] = bf16_rne(pv[ct][r]);
        __syncthreads();   // all waves done reading K; P not cross-wave

#pragma unroll
        for (int p = 0; p < 4; p++) {
            int idx = tid + p * 256;           // 0..1023
            int d = idx >> 3, seg = idx & 7;
            *(uint4*)&uni[d * 72 + seg * 8] =
                *(const uint4*)(Vth + zoff + (long long)d * SDIM + t0 + seg * 8);
        }
        __syncthreads();

        bf16x8 pa[2];
#pragma unroll
        for (int ks = 0; ks < 2; ks++)
            pa[ks] = *(const bf16x8*)&pls[(w * 16 + l16) * 72 + ks * 32 + quad * 8];
#pragma unroll
        for (int dt = 0; dt < 8; dt++) {
            f32x4 o = oacc[dt];
#pragma unroll
            for (int ks = 0; ks < 2; ks++) {
                bf16x8 vb = *(const bf16x8*)&uni[(dt * 16 + l16) * 72 + ks * 32 + quad * 8];
                o = __builtin_amdgcn_mfma_f32_16x16x32_bf16(pa[ks], vb, o, 0, 0, 0);
            }
            oacc[dt] = o;
        }
    }

    float inv[4];
#pragma unroll
    for (int r = 0; r < 4; r++) inv[r] = 1.0f / lsum[r];
#pragma unroll
    for (int dt = 0; dt < 8; dt++)
#pragma unroll
        for (int r = 0; r < 4; r++) {
            float v = oacc[dt][r] * inv[r];
            int srow = q0 + w * 16 + quad * 4 + r;
            int d = dt * 16 + l16;
            long long idx = (long long)b * SDIM * EDIM + (long long)srow * EDIM + h * DDIM + d;
            u16 hh = bf16_rne(v);
            Oh[idx] = hh;
            Ol[idx] = bf16_rne(v - bf16f(hh));
        }
}

// ---------------------------------------------------------------------------
// expmap0: rows of 128 (h+l read, h-only write). 256 thr = 4 rows/block.
// grid.y 0 -> q, 1 -> k.
// ---------------------------------------------------------------------------
__global__ __launch_bounds__(256) void expmap_k(
    u16* __restrict__ qh, const u16* __restrict__ ql,
    u16* __restrict__ kh, const u16* __restrict__ kl)
{
    long long row = (long long)blockIdx.x * 4 + (threadIdx.x >> 6);
    u16* h = (blockIdx.y == 0 ? qh : kh) + row * DDIM;
    const u16* l = (blockIdx.y == 0 ? ql : kl) + row * DDIM;
    const int lane = threadIdx.x & 63;
    float v0 = bf16f(h[lane]) + bf16f(l[lane]);
    float v1 = bf16f(h[lane + 64]) + bf16f(l[lane + 64]);
    float s = v0 * v0 + v1 * v1;
#pragma unroll
    for (int off = 32; off > 0; off >>= 1) s += __shfl_down(s, off, 64);
    s = __shfl(s, 0, 64);
    float n = fmaxf(sqrtf(s), 1e-6f);
    float scl = tanhf(n) / n;
    h[lane] = bf16_rne(v0 * scl);
    h[lane + 64] = bf16_rne(v1 * scl);
}

// ---------------------------------------------------------------------------
// Generic 64x64-tile transpose: dst[c][r] = src[r][c]. grid (rT, cT, nz).
// ---------------------------------------------------------------------------
__global__ __launch_bounds__(256) void transpose_g(
    const u16* __restrict__ src, u16* __restrict__ dst,
    int ldS, int ldD, long long sZ, long long dZ)
{
    __shared__ __align__(16) u16 tl[64][72];
    const int r0 = blockIdx.x * 64, c0 = blockIdx.y * 64;
    const u16* s = src + (long long)blockIdx.z * sZ;
    u16* d = dst + (long long)blockIdx.z * dZ;
    const int t = threadIdx.x;
    const int sr = t >> 2, dc = (t & 3) * 16;
    {
        const u16* p = s + (long long)(r0 + sr) * ldS + c0 + dc;
        *(uint4*)&tl[sr][dc]     = *(const uint4*)p;
        *(uint4*)&tl[sr][dc + 8] = *(const uint4*)(p + 8);
    }
    __syncthreads();
    const int dr = t >> 2, sc = (t & 3) * 16;
    unsigned wbuf[8];
#pragma unroll
    for (int i = 0; i < 8; i++)
        wbuf[i] = (unsigned)tl[sc + 2 * i][dr] | ((unsigned)tl[sc + 2 * i + 1][dr] << 16);
    u16* po = d + (long long)(c0 + dr) * ldD + r0 + sc;
    *(uint4*)po = make_uint4(wbuf[0], wbuf[1], wbuf[2], wbuf[3]);
    *(uint4*)(po + 8) = make_uint4(wbuf[4], wbuf[5], wbuf[6], wbuf[7]);
}

// final output: f32 = h + l (zero-fill past nmax)
__global__ __launch_bounds__(256) void out_k(
    const u16* __restrict__ h, const u16* __restrict__ l,
    float* __restrict__ out, long long n, long long nmax)
{
    long long i = (long long)blockIdx.x * 256 + threadIdx.x;
    if (i < n) out[i] = (i < nmax) ? (bf16f(h[i]) + bf16f(l[i])) : 0.f;
}

#define N2   2097152LL            // B*S*E == NZ*S*D
#define W3N  3145728LL            // 3E*E
#define WON  1048576LL            // E*E
#define WHN  49152LL              // 3*D*D
#define EE   1048576LL            // E*E

extern "C" void kernel_launch(void* const* d_in, const int* in_sizes, int n_in,
                              void* d_out, int out_size, void* d_ws, size_t ws_size,
                              hipStream_t stream)
{
    const float* x       = (const float*)d_in[0];
    const float* Wqkv    = (const float*)d_in[1];
    const float* Wq      = (const float*)d_in[3];
    const float* Wk      = (const float*)d_in[5];
    const float* Wv      = (const float*)d_in[7];
    const float* Wout    = (const float*)d_in[9];
    const float* Wlayers = (const float*)d_in[11];

    u16* ws = (u16*)d_ws;
    long long o = 0;
    u16 *curh = ws + o; o += N2;  u16 *curl = ws + o; o += N2;
    u16 *qkvh = ws + o; o += 3 * N2; u16 *qkvl = ws + o; o += 3 * N2;
    u16 *vth  = ws + o; o += N2;
    u16 *aoh  = ws + o; o += N2;  u16 *aol  = ws + o; o += N2;
    u16 *wqh  = ws + o; o += W3N; u16 *wql  = ws + o; o += W3N;
    u16 *wqth = ws + o; o += W3N; u16 *wqtl = ws + o; o += W3N;
    u16 *wfh  = ws + o; o += W3N; u16 *wfl  = ws + o; o += W3N;
    u16 *whh  = ws + o; o += WHN; u16 *whl  = ws + o; o += WHN;
    u16 *woh  = ws + o; o += WON; u16 *wol  = ws + o; o += WON;
    u16 *woth = ws + o; o += WON; u16 *wotl = ws + o; o += WON;
    u16 *wlh  = ws + o; o += W3N; u16 *wll  = ws + o; o += W3N;
    u16 *wloh = ws + o; o += W3N; u16 *wlol = ws + o; o += W3N;
    // total 58.8M u16 = 117.6 MB < 184 MB (R1-verified)

    // ---- one-time: splits ----
    split_k<<<2048, 256, 0, stream>>>(x, curh, curl, N2 / 4);
    split_k<<<3072, 256, 0, stream>>>(Wqkv, wqh, wql, W3N / 4);
    split_k<<<16, 256, 0, stream>>>(Wq, whh, whl, 4096);
    split_k<<<16, 256, 0, stream>>>(Wk, whh + 16384, whl + 16384, 4096);
    split_k<<<16, 256, 0, stream>>>(Wv, whh + 32768, whl + 32768, 4096);
    split_k<<<1024, 256, 0, stream>>>(Wout, woh, wol, WON / 4);
    split_k<<<3072, 256, 0, stream>>>(Wlayers, wlh, wll, W3N / 4);

    // ---- one-time: transposes ----
    transpose_g<<<dim3(48, 16, 1), 256, 0, stream>>>(wqh, wqth, EDIM, 3 * EDIM, 0, 0);
    transpose_g<<<dim3(48, 16, 1), 256, 0, stream>>>(wql, wqtl, EDIM, 3 * EDIM, 0, 0);
    transpose_g<<<dim3(16, 16, 1), 256, 0, stream>>>(woh, woth, EDIM, EDIM, 0, 0);
    transpose_g<<<dim3(16, 16, 1), 256, 0, stream>>>(wol, wotl, EDIM, EDIM, 0, 0);

    // ---- one-time: Wfused[pE+hD+d, e] = sum_d' Whead_p[d,d'] * Wqkv[pE+hD+d', e]
    // z = p*8 + h (Bdec=1, Hdec=8): M=128 (d), N=1024 (e), K=128.
    gemm3<<<dim3(8, 1, 24), 256, 0, stream>>>(
        whh, whl, 0, DDIM, (long long)DDIM * DDIM, 0, 0,
        wqth, wqtl, 0, 3 * EDIM, EDIM, 0, DDIM,
        wfh, wfl, 0, EDIM, (long long)EDIM * EDIM, 0, (long long)DDIM * EDIM,
        1, 8, DDIM, 1.0f, 0);

    // ---- one-time: Wlo[l] = Wlayers[l] @ Wout (z = layer) ----
    gemm3<<<dim3(8, 8, 3), 256, 0, stream>>>(
        wlh, wll, 0, EDIM, EE, 0, 0,
        woth, wotl, 0, EDIM, 0, 0, 0,
        wloh, wlol, 0, EDIM, EE, 0, 0,
        1, 1, EDIM, 1.0f, 0);

    for (int layer = 0; layer < LNUM; layer++) {
        // qkv fused: z = p*16 + b*8 + h (Bdec=2, Hdec=8): M=1024(s), N=128(d), K=1024
        gemm3<<<dim3(1, 8, 48), 256, 0, stream>>>(
            curh, curl, 0, EDIM, 0, (long long)SDIM * EDIM, 0,
            wfh, wfl, 0, EDIM, EE, 0, (long long)DDIM * EDIM,
            qkvh, qkvl, 0, DDIM, N2, (long long)HDIM * SDIM * DDIM, (long long)SDIM * DDIM,
            2, 8, EDIM, 1.0f, 0);

        // expmap0 on q,k (h-plane output)
        expmap_k<<<dim3(NZ * SDIM / 4, 2), 256, 0, stream>>>(
            qkvh, qkvl, qkvh + N2, qkvl + N2);

        // Vt[z][D][S] = V[z]^T (h only)
        transpose_g<<<dim3(16, 2, NZ), 256, 0, stream>>>(
            qkvh + 2 * N2, vth, DDIM, SDIM, (long long)SDIM * DDIM, (long long)SDIM * DDIM);

        // fused attention -> attnout split
        flash_k<<<dim3(16, 1, NZ), 256, 0, stream>>>(
            qkvh, qkvh + N2, vth, aoh, aol);

        // cur += attnout @ Wlo[layer]^T
        gemm3<<<dim3(8, 16, 1), 256, 0, stream>>>(
            aoh, aol, 0, EDIM, 0, 0, 0,
            wloh, wlol, (long long)layer * EE, EDIM, 0, 0, 0,
            curh, curl, 0, EDIM, 0, 0, 0,
            1, 1, EDIM, 1.0f, 1);
    }

    out_k<<<(out_size + 255) / 256, 256, 0, stream>>>(
        curh, curl, (float*)d_out, out_size, N2);
}

// Round 10
// 641.878 us; speedup vs baseline: 1.6218x; 1.0948x over previous
//
#include <hip/hip_runtime.h>
#include <math.h>

// Problem constants (reference: B=2,S=1024,E=1024,H=8,D=128,L=3)
#define BDIM 2
#define SDIM 1024
#define EDIM 1024
#define HDIM 8
#define DDIM 128
#define LNUM 3
#define NZ 16
#define SCALE_F 0.08838834764831845f

// WORLD MODEL (verified R6-R9): complex64 lowered to f32 REAL-PART-ONLY.
// Precision design: residual stream `cur` + weight folds = bf16x3 split;
// activation path (qkv, attention, attnout) = single bf16 (error ~2e-3 abs,
// systematic floor is 0.0625 of 0.0994 threshold).
// R10: flash_k 4->2 barriers + reg double-buffer prefetch; gemm1 (single-bf16
// A/B, split-C accumulate) for qkv + output GEMMs.

typedef unsigned short u16;
typedef __attribute__((ext_vector_type(8))) short bf16x8;
typedef __attribute__((ext_vector_type(4))) float f32x4;

__device__ __forceinline__ u16 bf16_rne(float x) {
    unsigned u = __float_as_uint(x);
    u += 0x7FFFu + ((u >> 16) & 1u);
    return (u16)(u >> 16);
}
__device__ __forceinline__ float bf16f(u16 h) {
    return __uint_as_float(((unsigned)h) << 16);
}

// ---------------------------------------------------------------------------
__global__ __launch_bounds__(256) void split_k(
    const float* __restrict__ in, u16* __restrict__ h, u16* __restrict__ l,
    long long n4)
{
    long long i = (long long)blockIdx.x * 256 + threadIdx.x;
    if (i >= n4) return;
    float4 v = ((const float4*)in)[i];
    float vv[4] = { v.x, v.y, v.z, v.w };
    u16 hh[4], ll[4];
#pragma unroll
    for (int j = 0; j < 4; j++) {
        hh[j] = bf16_rne(vv[j]);
        ll[j] = bf16_rne(vv[j] - bf16f(hh[j]));
    }
    ((uint2*)h)[i] = make_uint2((unsigned)hh[0] | ((unsigned)hh[1] << 16),
                                (unsigned)hh[2] | ((unsigned)hh[3] << 16));
    ((uint2*)l)[i] = make_uint2((unsigned)ll[0] | ((unsigned)ll[1] << 16),
                                (unsigned)ll[2] | ((unsigned)ll[3] << 16));
}

// ---------------------------------------------------------------------------
// bf16x3 split GEMM (weights folds only). Tile 128x128x32.
// ---------------------------------------------------------------------------
__global__ __launch_bounds__(256) void gemm3(
    const u16* __restrict__ Ah, const u16* __restrict__ Al,
    long long aOff, int lda, long long aSP, long long aSB, long long aSH,
    const u16* __restrict__ Bh, const u16* __restrict__ Bl,
    long long bOff, int ldb, long long bSP, long long bSB, long long bSH,
    u16* __restrict__ Ch, u16* __restrict__ Cl,
    long long cOff, int ldc, long long cSP, long long cSB, long long cSH,
    int Bdec, int Hdec, int K, float alpha, int accum)
{
    __shared__ __align__(16) u16 AhL[4][128][8];
    __shared__ __align__(16) u16 AlL[4][128][8];
    __shared__ __align__(16) u16 BhL[4][128][8];
    __shared__ __align__(16) u16 BlL[4][128][8];

    const int tid  = threadIdx.x;
    const int lane = tid & 63;
    const int wave = tid >> 6;
    const int quad = lane >> 4;
    const int l16  = lane & 15;
    const int z  = blockIdx.z;
    const int zp = z / (Bdec * Hdec);
    const int r  = z - zp * Bdec * Hdec;
    const int zb = r / Hdec, zh = r - zb * Hdec;
    const long long aBase = aOff + (long long)zp * aSP + (long long)zb * aSB + (long long)zh * aSH;
    const long long bBase = bOff + (long long)zp * bSP + (long long)zb * bSB + (long long)zh * bSH;
    const long long cBase = cOff + (long long)zp * cSP + (long long)zb * cSB + (long long)zh * cSH;
    const int bm = blockIdx.y * 128, bn = blockIdx.x * 128;
    const int wr = (wave >> 1) * 64, wc = (wave & 1) * 64;
    const int sm = tid >> 1;
    const int kh = (tid & 1) * 16;
    const int c0 = kh >> 3;

    const u16* gAh = Ah + aBase + (long long)(bm + sm) * lda + kh;
    const u16* gAl = Al + aBase + (long long)(bm + sm) * lda + kh;
    const u16* gBh = Bh + bBase + (long long)(bn + sm) * ldb + kh;
    const u16* gBl = Bl + bBase + (long long)(bn + sm) * ldb + kh;

    f32x4 acc[4][4];
#pragma unroll
    for (int i = 0; i < 4; i++)
#pragma unroll
        for (int j = 0; j < 4; j++) {
            acc[i][j][0] = 0.f; acc[i][j][1] = 0.f;
            acc[i][j][2] = 0.f; acc[i][j][3] = 0.f;
        }

    for (int k0 = 0; k0 < K; k0 += 32) {
        uint4 a0 = *(const uint4*)(gAh + k0);
        uint4 a1 = *(const uint4*)(gAh + k0 + 8);
        uint4 a2 = *(const uint4*)(gAl + k0);
        uint4 a3 = *(const uint4*)(gAl + k0 + 8);
        uint4 b0 = *(const uint4*)(gBh + k0);
        uint4 b1 = *(const uint4*)(gBh + k0 + 8);
        uint4 b2 = *(const uint4*)(gBl + k0);
        uint4 b3 = *(const uint4*)(gBl + k0 + 8);
        __syncthreads();
        *(uint4*)&AhL[c0][sm][0]     = a0;
        *(uint4*)&AhL[c0 + 1][sm][0] = a1;
        *(uint4*)&AlL[c0][sm][0]     = a2;
        *(uint4*)&AlL[c0 + 1][sm][0] = a3;
        *(uint4*)&BhL[c0][sm][0]     = b0;
        *(uint4*)&BhL[c0 + 1][sm][0] = b1;
        *(uint4*)&BlL[c0][sm][0]     = b2;
        *(uint4*)&BlL[c0 + 1][sm][0] = b3;
        __syncthreads();

        bf16x8 fah[4], fal[4], fbh[4], fbl[4];
#pragma unroll
        for (int i = 0; i < 4; i++) {
            fah[i] = *(const bf16x8*)&AhL[quad][wr + i * 16 + l16][0];
            fal[i] = *(const bf16x8*)&AlL[quad][wr + i * 16 + l16][0];
            fbh[i] = *(const bf16x8*)&BhL[quad][wc + i * 16 + l16][0];
            fbl[i] = *(const bf16x8*)&BlL[quad][wc + i * 16 + l16][0];
        }
#pragma unroll
        for (int i = 0; i < 4; i++)
#pragma unroll
            for (int j = 0; j < 4; j++) {
                acc[i][j] = __builtin_amdgcn_mfma_f32_16x16x32_bf16(fah[i], fbh[j], acc[i][j], 0, 0, 0);
                acc[i][j] = __builtin_amdgcn_mfma_f32_16x16x32_bf16(fah[i], fbl[j], acc[i][j], 0, 0, 0);
                acc[i][j] = __builtin_amdgcn_mfma_f32_16x16x32_bf16(fal[i], fbh[j], acc[i][j], 0, 0, 0);
            }
    }

#pragma unroll
    for (int i = 0; i < 4; i++)
#pragma unroll
        for (int j = 0; j < 4; j++)
#pragma unroll
            for (int rr = 0; rr < 4; rr++) {
                int m = bm + wr + i * 16 + quad * 4 + rr;
                int n = bn + wc + j * 16 + l16;
                long long ci = cBase + (long long)m * ldc + n;
                float c = acc[i][j][rr] * alpha;
                if (accum) c += bf16f(Ch[ci]) + bf16f(Cl[ci]);
                u16 hh = bf16_rne(c);
                Ch[ci] = hh;
                Cl[ci] = bf16_rne(c - bf16f(hh));
            }
}

// ---------------------------------------------------------------------------
// Single-bf16 GEMM (activation path). A/B single h-plane; C split h/l with
// optional split accumulate and optional l-store. Tile 128x128x32.
// ---------------------------------------------------------------------------
__global__ __launch_bounds__(256) void gemm1(
    const u16* __restrict__ Ah,
    long long aOff, int lda, long long aSP, long long aSB, long long aSH,
    const u16* __restrict__ Bh,
    long long bOff, int ldb, long long bSP, long long bSB, long long bSH,
    u16* __restrict__ Ch, u16* __restrict__ Cl,
    long long cOff, int ldc, long long cSP, long long cSB, long long cSH,
    int Bdec, int Hdec, int K, float alpha, int accum, int storeL)
{
    __shared__ __align__(16) u16 AhL[4][128][8];
    __shared__ __align__(16) u16 BhL[4][128][8];

    const int tid  = threadIdx.x;
    const int lane = tid & 63;
    const int wave = tid >> 6;
    const int quad = lane >> 4;
    const int l16  = lane & 15;
    const int z  = blockIdx.z;
    const int zp = z / (Bdec * Hdec);
    const int r  = z - zp * Bdec * Hdec;
    const int zb = r / Hdec, zh = r - zb * Hdec;
    const long long aBase = aOff + (long long)zp * aSP + (long long)zb * aSB + (long long)zh * aSH;
    const long long bBase = bOff + (long long)zp * bSP + (long long)zb * bSB + (long long)zh * bSH;
    const long long cBase = cOff + (long long)zp * cSP + (long long)zb * cSB + (long long)zh * cSH;
    const int bm = blockIdx.y * 128, bn = blockIdx.x * 128;
    const int wr = (wave >> 1) * 64, wc = (wave & 1) * 64;
    const int sm = tid >> 1;
    const int kh = (tid & 1) * 16;
    const int c0 = kh >> 3;

    const u16* gAh = Ah + aBase + (long long)(bm + sm) * lda + kh;
    const u16* gBh = Bh + bBase + (long long)(bn + sm) * ldb + kh;

    f32x4 acc[4][4];
#pragma unroll
    for (int i = 0; i < 4; i++)
#pragma unroll
        for (int j = 0; j < 4; j++) {
            acc[i][j][0] = 0.f; acc[i][j][1] = 0.f;
            acc[i][j][2] = 0.f; acc[i][j][3] = 0.f;
        }

    for (int k0 = 0; k0 < K; k0 += 32) {
        uint4 a0 = *(const uint4*)(gAh + k0);
        uint4 a1 = *(const uint4*)(gAh + k0 + 8);
        uint4 b0 = *(const uint4*)(gBh + k0);
        uint4 b1 = *(const uint4*)(gBh + k0 + 8);
        __syncthreads();
        *(uint4*)&AhL[c0][sm][0]     = a0;
        *(uint4*)&AhL[c0 + 1][sm][0] = a1;
        *(uint4*)&BhL[c0][sm][0]     = b0;
        *(uint4*)&BhL[c0 + 1][sm][0] = b1;
        __syncthreads();

        bf16x8 fah[4], fbh[4];
#pragma unroll
        for (int i = 0; i < 4; i++) {
            fah[i] = *(const bf16x8*)&AhL[quad][wr + i * 16 + l16][0];
            fbh[i] = *(const bf16x8*)&BhL[quad][wc + i * 16 + l16][0];
        }
#pragma unroll
        for (int i = 0; i < 4; i++)
#pragma unroll
            for (int j = 0; j < 4; j++)
                acc[i][j] = __builtin_amdgcn_mfma_f32_16x16x32_bf16(fah[i], fbh[j], acc[i][j], 0, 0, 0);
    }

#pragma unroll
    for (int i = 0; i < 4; i++)
#pragma unroll
        for (int j = 0; j < 4; j++)
#pragma unroll
            for (int rr = 0; rr < 4; rr++) {
                int m = bm + wr + i * 16 + quad * 4 + rr;
                int n = bn + wc + j * 16 + l16;
                long long ci = cBase + (long long)m * ldc + n;
                float c = acc[i][j][rr] * alpha;
                if (accum) c += bf16f(Ch[ci]) + bf16f(Cl[ci]);
                u16 hh = bf16_rne(c);
                Ch[ci] = hh;
                if (storeL) Cl[ci] = bf16_rne(c - bf16f(hh));
            }
}

// ---------------------------------------------------------------------------
// Flash attention, single-bf16, 2 barriers/iter + register double-buffer
// prefetch. Per block: one 64-row Q tile of one z=(b,h).
// ---------------------------------------------------------------------------
__global__ __launch_bounds__(256) void flash_k(
    const u16* __restrict__ Qh, const u16* __restrict__ Kh,
    const u16* __restrict__ Vth, u16* __restrict__ Oh)
{
    __shared__ __align__(16) u16 Kls[64 * 136];    // [t][136]
    __shared__ __align__(16) u16 Vls[128 * 72];    // [d][72]
    __shared__ __align__(16) u16 pls[64 * 72];     // [q][72]

    const int tid  = threadIdx.x;
    const int lane = tid & 63;
    const int w    = tid >> 6;
    const int quad = lane >> 4;
    const int l16  = lane & 15;
    const int z    = blockIdx.z;
    const int q0   = blockIdx.x * 64;
    const long long zoff = (long long)z * SDIM * DDIM;
    const int b = z >> 3, h = z & 7;

    int kt[4], ks[4], vd[4], vs[4];
#pragma unroll
    for (int p = 0; p < 4; p++) {
        int idx = tid + p * 256;
        kt[p] = idx >> 4; ks[p] = (idx & 15) * 8;
        vd[p] = idx >> 3; vs[p] = (idx & 7) * 8;
    }

    const u16* qr = Qh + zoff + (long long)(q0 + w * 16 + l16) * DDIM;
    bf16x8 qf[4];
#pragma unroll
    for (int s = 0; s < 4; s++) qf[s] = *(const bf16x8*)(qr + s * 32 + quad * 8);

    uint4 rk[2][4], rv[2][4];
#pragma unroll
    for (int p = 0; p < 4; p++) {
        rk[0][p] = *(const uint4*)(Kh + zoff + (long long)kt[p] * DDIM + ks[p]);
        rv[0][p] = *(const uint4*)(Vth + zoff + (long long)vd[p] * SDIM + vs[p]);
    }

    f32x4 oacc[8];
#pragma unroll
    for (int dt = 0; dt < 8; dt++) {
        oacc[dt][0] = 0.f; oacc[dt][1] = 0.f; oacc[dt][2] = 0.f; oacc[dt][3] = 0.f;
    }
    float mold[4] = { -1e30f, -1e30f, -1e30f, -1e30f };
    float lsum[4] = { 0.f, 0.f, 0.f, 0.f };

#pragma unroll 2
    for (int t0 = 0; t0 < SDIM; t0 += 64) {
        const int pb = (t0 >> 6) & 1;
        __syncthreads();   // previous iteration's readers done
#pragma unroll
        for (int p = 0; p < 4; p++) {
            *(uint4*)&Kls[kt[p] * 136 + ks[p]] = rk[pb][p];
            *(uint4*)&Vls[vd[p] * 72 + vs[p]]  = rv[pb][p];
        }
        if (t0 + 64 < SDIM) {
#pragma unroll
            for (int p = 0; p < 4; p++) {
                rk[pb ^ 1][p] = *(const uint4*)(Kh + zoff + (long long)(t0 + 64 + kt[p]) * DDIM + ks[p]);
                rv[pb ^ 1][p] = *(const uint4*)(Vth + zoff + (long long)vd[p] * SDIM + (t0 + 64) + vs[p]);
            }
        }
        __syncthreads();   // LDS tiles visible (prefetch stays in flight)

        // ---- S = Q K^T ----
        f32x4 sacc[4];
#pragma unroll
        for (int ct = 0; ct < 4; ct++) {
            f32x4 a; a[0] = 0.f; a[1] = 0.f; a[2] = 0.f; a[3] = 0.f;
#pragma unroll
            for (int s = 0; s < 4; s++) {
                bf16x8 kb = *(const bf16x8*)&Kls[(ct * 16 + l16) * 136 + s * 32 + quad * 8];
                a = __builtin_amdgcn_mfma_f32_16x16x32_bf16(qf[s], kb, a, 0, 0, 0);
            }
            sacc[ct] = a;
        }

        // ---- online softmax ----
        float pv[4][4], alpha[4];
#pragma unroll
        for (int r = 0; r < 4; r++) {
            float mx = -1e30f;
#pragma unroll
            for (int ct = 0; ct < 4; ct++) mx = fmaxf(mx, sacc[ct][r] * SCALE_F);
#pragma unroll
            for (int msk = 1; msk < 16; msk <<= 1) mx = fmaxf(mx, __shfl_xor(mx, msk, 64));
            float mnew = fmaxf(mold[r], mx);
            alpha[r] = expf(mold[r] - mnew);
            float rs = 0.f;
#pragma unroll
            for (int ct = 0; ct < 4; ct++) {
                float p = expf(sacc[ct][r] * SCALE_F - mnew);
                pv[ct][r] = p; rs += p;
            }
#pragma unroll
            for (int msk = 1; msk < 16; msk <<= 1) rs += __shfl_xor(rs, msk, 64);
            lsum[r] = lsum[r] * alpha[r] + rs;
            mold[r] = mnew;
        }
#pragma unroll
        for (int dt = 0; dt < 8; dt++)
#pragma unroll
            for (int r = 0; r < 4; r++) oacc[dt][r] *= alpha[r];

        // ---- P to LDS (wave-private band; no barrier needed) ----
#pragma unroll
        for (int ct = 0; ct < 4; ct++)
#pragma unroll
            for (int r = 0; r < 4; r++)
                pls[(w * 16 + quad * 4 + r) * 72 + ct * 16 + l16] = bf16_rne(pv[ct][r]);

        // ---- O += P V ----
        bf16x8 pa[2];
#pragma unroll
        for (int ks2 = 0; ks2 < 2; ks2++)
            pa[ks2] = *(const bf16x8*)&pls[(w * 16 + l16) * 72 + ks2 * 32 + quad * 8];
#pragma unroll
        for (int dt = 0; dt < 8; dt++) {
            f32x4 o = oacc[dt];
#pragma unroll
            for (int ks2 = 0; ks2 < 2; ks2++) {
                bf16x8 vb = *(const bf16x8*)&Vls[(dt * 16 + l16) * 72 + ks2 * 32 + quad * 8];
                o = __builtin_amdgcn_mfma_f32_16x16x32_bf16(pa[ks2], vb, o, 0, 0, 0);
            }
            oacc[dt] = o;
        }
    }

    float inv[4];
#pragma unroll
    for (int r = 0; r < 4; r++) inv[r] = 1.0f / lsum[r];
#pragma unroll
    for (int dt = 0; dt < 8; dt++)
#pragma unroll
        for (int r = 0; r < 4; r++) {
            float v = oacc[dt][r] * inv[r];
            int srow = q0 + w * 16 + quad * 4 + r;
            int d = dt * 16 + l16;
            Oh[(long long)b * SDIM * EDIM + (long long)srow * EDIM + h * DDIM + d] = bf16_rne(v);
        }
}

// ---------------------------------------------------------------------------
// expmap0 (h-plane only): rows of 128. 256 thr = 4 rows/block. grid.y: 0=q,1=k.
// ---------------------------------------------------------------------------
__global__ __launch_bounds__(256) void expmap_k(
    u16* __restrict__ qh, u16* __restrict__ kh)
{
    long long row = (long long)blockIdx.x * 4 + (threadIdx.x >> 6);
    u16* h = (blockIdx.y == 0 ? qh : kh) + row * DDIM;
    const int lane = threadIdx.x & 63;
    float v0 = bf16f(h[lane]);
    float v1 = bf16f(h[lane + 64]);
    float s = v0 * v0 + v1 * v1;
#pragma unroll
    for (int off = 32; off > 0; off >>= 1) s += __shfl_down(s, off, 64);
    s = __shfl(s, 0, 64);
    float n = fmaxf(sqrtf(s), 1e-6f);
    float scl = tanhf(n) / n;
    h[lane] = bf16_rne(v0 * scl);
    h[lane + 64] = bf16_rne(v1 * scl);
}

// ---------------------------------------------------------------------------
// Generic 64x64-tile transpose: dst[c][r] = src[r][c]. grid (rT, cT, nz).
// ---------------------------------------------------------------------------
__global__ __launch_bounds__(256) void transpose_g(
    const u16* __restrict__ src, u16* __restrict__ dst,
    int ldS, int ldD, long long sZ, long long dZ)
{
    __shared__ __align__(16) u16 tl[64][72];
    const int r0 = blockIdx.x * 64, c0 = blockIdx.y * 64;
    const u16* s = src + (long long)blockIdx.z * sZ;
    u16* d = dst + (long long)blockIdx.z * dZ;
    const int t = threadIdx.x;
    const int sr = t >> 2, dc = (t & 3) * 16;
    {
        const u16* p = s + (long long)(r0 + sr) * ldS + c0 + dc;
        *(uint4*)&tl[sr][dc]     = *(const uint4*)p;
        *(uint4*)&tl[sr][dc + 8] = *(const uint4*)(p + 8);
    }
    __syncthreads();
    const int dr = t >> 2, sc = (t & 3) * 16;
    unsigned wbuf[8];
#pragma unroll
    for (int i = 0; i < 8; i++)
        wbuf[i] = (unsigned)tl[sc + 2 * i][dr] | ((unsigned)tl[sc + 2 * i + 1][dr] << 16);
    u16* po = d + (long long)(c0 + dr) * ldD + r0 + sc;
    *(uint4*)po = make_uint4(wbuf[0], wbuf[1], wbuf[2], wbuf[3]);
    *(uint4*)(po + 8) = make_uint4(wbuf[4], wbuf[5], wbuf[6], wbuf[7]);
}

// final output: f32 = h + l (zero-fill past nmax)
__global__ __launch_bounds__(256) void out_k(
    const u16* __restrict__ h, const u16* __restrict__ l,
    float* __restrict__ out, long long n, long long nmax)
{
    long long i = (long long)blockIdx.x * 256 + threadIdx.x;
    if (i < n) out[i] = (i < nmax) ? (bf16f(h[i]) + bf16f(l[i])) : 0.f;
}

#define N2   2097152LL            // B*S*E == NZ*S*D
#define W3N  3145728LL            // 3E*E
#define WON  1048576LL            // E*E
#define WHN  49152LL              // 3*D*D
#define EE   1048576LL            // E*E

extern "C" void kernel_launch(void* const* d_in, const int* in_sizes, int n_in,
                              void* d_out, int out_size, void* d_ws, size_t ws_size,
                              hipStream_t stream)
{
    const float* x       = (const float*)d_in[0];
    const float* Wqkv    = (const float*)d_in[1];
    const float* Wq      = (const float*)d_in[3];
    const float* Wk      = (const float*)d_in[5];
    const float* Wv      = (const float*)d_in[7];
    const float* Wout    = (const float*)d_in[9];
    const float* Wlayers = (const float*)d_in[11];

    u16* ws = (u16*)d_ws;
    long long o = 0;
    u16 *curh = ws + o; o += N2;  u16 *curl = ws + o; o += N2;
    u16 *qkvh = ws + o; o += 3 * N2;
    u16 *vth  = ws + o; o += N2;
    u16 *aoh  = ws + o; o += N2;
    u16 *wqh  = ws + o; o += W3N; u16 *wql  = ws + o; o += W3N;
    u16 *wqth = ws + o; o += W3N; u16 *wqtl = ws + o; o += W3N;
    u16 *wfh  = ws + o; o += W3N; u16 *wfl  = ws + o; o += W3N;
    u16 *whh  = ws + o; o += WHN; u16 *whl  = ws + o; o += WHN;
    u16 *woh  = ws + o; o += WON; u16 *wol  = ws + o; o += WON;
    u16 *woth = ws + o; o += WON; u16 *wotl = ws + o; o += WON;
    u16 *wlh  = ws + o; o += W3N; u16 *wll  = ws + o; o += W3N;
    u16 *wloh = ws + o; o += W3N; u16 *wlol = ws + o; o += W3N;
    // total ~48.3M u16 = 96.6 MB < 184 MB (R1-verified)

    // ---- one-time: splits ----
    split_k<<<2048, 256, 0, stream>>>(x, curh, curl, N2 / 4);
    split_k<<<3072, 256, 0, stream>>>(Wqkv, wqh, wql, W3N / 4);
    split_k<<<16, 256, 0, stream>>>(Wq, whh, whl, 4096);
    split_k<<<16, 256, 0, stream>>>(Wk, whh + 16384, whl + 16384, 4096);
    split_k<<<16, 256, 0, stream>>>(Wv, whh + 32768, whl + 32768, 4096);
    split_k<<<1024, 256, 0, stream>>>(Wout, woh, wol, WON / 4);
    split_k<<<3072, 256, 0, stream>>>(Wlayers, wlh, wll, W3N / 4);

    // ---- one-time: transposes ----
    transpose_g<<<dim3(48, 16, 1), 256, 0, stream>>>(wqh, wqth, EDIM, 3 * EDIM, 0, 0);
    transpose_g<<<dim3(48, 16, 1), 256, 0, stream>>>(wql, wqtl, EDIM, 3 * EDIM, 0, 0);
    transpose_g<<<dim3(16, 16, 1), 256, 0, stream>>>(woh, woth, EDIM, EDIM, 0, 0);
    transpose_g<<<dim3(16, 16, 1), 256, 0, stream>>>(wol, wotl, EDIM, EDIM, 0, 0);

    // ---- one-time: Wfused[pE+hD+d, e] = sum_d' Whead_p[d,d'] * Wqkv[pE+hD+d', e]
    gemm3<<<dim3(8, 1, 24), 256, 0, stream>>>(
        whh, whl, 0, DDIM, (long long)DDIM * DDIM, 0, 0,
        wqth, wqtl, 0, 3 * EDIM, EDIM, 0, DDIM,
        wfh, wfl, 0, EDIM, (long long)EDIM * EDIM, 0, (long long)DDIM * EDIM,
        1, 8, DDIM, 1.0f, 0);

    // ---- one-time: Wlo[l] = Wlayers[l] @ Wout ----
    gemm3<<<dim3(8, 8, 3), 256, 0, stream>>>(
        wlh, wll, 0, EDIM, EE, 0, 0,
        woth, wotl, 0, EDIM, 0, 0, 0,
        wloh, wlol, 0, EDIM, EE, 0, 0,
        1, 1, EDIM, 1.0f, 0);

    for (int layer = 0; layer < LNUM; layer++) {
        // qkv fused (single-bf16): z = p*16 + b*8 + h: M=1024(s), N=128(d), K=1024
        gemm1<<<dim3(1, 8, 48), 256, 0, stream>>>(
            curh, 0, EDIM, 0, (long long)SDIM * EDIM, 0,
            wfh, 0, EDIM, EE, 0, (long long)DDIM * EDIM,
            qkvh, qkvh, 0, DDIM, N2, (long long)HDIM * SDIM * DDIM, (long long)SDIM * DDIM,
            2, 8, EDIM, 1.0f, 0, 0);

        // expmap0 on q,k
        expmap_k<<<dim3(NZ * SDIM / 4, 2), 256, 0, stream>>>(qkvh, qkvh + N2);

        // Vt[z][D][S] = V[z]^T
        transpose_g<<<dim3(16, 2, NZ), 256, 0, stream>>>(
            qkvh + 2 * N2, vth, DDIM, SDIM, (long long)SDIM * DDIM, (long long)SDIM * DDIM);

        // fused attention -> attnout (h only)
        flash_k<<<dim3(16, 1, NZ), 256, 0, stream>>>(
            qkvh, qkvh + N2, vth, aoh);

        // cur += attnout @ Wlo[layer]^T  (A/B single, C split accumulate)
        gemm1<<<dim3(8, 16, 1), 256, 0, stream>>>(
            aoh, 0, EDIM, 0, 0, 0,
            wloh, (long long)layer * EE, EDIM, 0, 0, 0,
            curh, curl, 0, EDIM, 0, 0, 0,
            1, 1, EDIM, 1.0f, 1, 1);
    }

    out_k<<<(out_size + 255) / 256, 256, 0, stream>>>(
        curh, curl, (float*)d_out, out_size, N2);
}

// Round 11
// 606.822 us; speedup vs baseline: 1.7155x; 1.0578x over previous
//
#include <hip/hip_runtime.h>
#include <math.h>

// Problem constants (reference: B=2,S=1024,E=1024,H=8,D=128,L=3)
#define BDIM 2
#define SDIM 1024
#define EDIM 1024
#define HDIM 8
#define DDIM 128
#define LNUM 3
#define NZ 16
#define NPART 4
#define SCALE_F 0.08838834764831845f

// WORLD MODEL (verified R6-R10): complex64 lowered to f32 REAL-PART-ONLY.
// Precision: residual `cur` + weight folds bf16x3; activation path single bf16.
// R11: flash split-K (4 parts, 1024 blocks) + combine kernel; no reg prefetch
// (R10's prefetch spilled to scratch: WRITE_SIZE 8->128 MB).

typedef unsigned short u16;
typedef __attribute__((ext_vector_type(8))) short bf16x8;
typedef __attribute__((ext_vector_type(4))) float f32x4;

__device__ __forceinline__ u16 bf16_rne(float x) {
    unsigned u = __float_as_uint(x);
    u += 0x7FFFu + ((u >> 16) & 1u);
    return (u16)(u >> 16);
}
__device__ __forceinline__ float bf16f(u16 h) {
    return __uint_as_float(((unsigned)h) << 16);
}

// ---------------------------------------------------------------------------
__global__ __launch_bounds__(256) void split_k(
    const float* __restrict__ in, u16* __restrict__ h, u16* __restrict__ l,
    long long n4)
{
    long long i = (long long)blockIdx.x * 256 + threadIdx.x;
    if (i >= n4) return;
    float4 v = ((const float4*)in)[i];
    float vv[4] = { v.x, v.y, v.z, v.w };
    u16 hh[4], ll[4];
#pragma unroll
    for (int j = 0; j < 4; j++) {
        hh[j] = bf16_rne(vv[j]);
        ll[j] = bf16_rne(vv[j] - bf16f(hh[j]));
    }
    ((uint2*)h)[i] = make_uint2((unsigned)hh[0] | ((unsigned)hh[1] << 16),
                                (unsigned)hh[2] | ((unsigned)hh[3] << 16));
    ((uint2*)l)[i] = make_uint2((unsigned)ll[0] | ((unsigned)ll[1] << 16),
                                (unsigned)ll[2] | ((unsigned)ll[3] << 16));
}

// ---------------------------------------------------------------------------
// bf16x3 split GEMM (weight folds only). Tile 128x128x32.
// ---------------------------------------------------------------------------
__global__ __launch_bounds__(256) void gemm3(
    const u16* __restrict__ Ah, const u16* __restrict__ Al,
    long long aOff, int lda, long long aSP, long long aSB, long long aSH,
    const u16* __restrict__ Bh, const u16* __restrict__ Bl,
    long long bOff, int ldb, long long bSP, long long bSB, long long bSH,
    u16* __restrict__ Ch, u16* __restrict__ Cl,
    long long cOff, int ldc, long long cSP, long long cSB, long long cSH,
    int Bdec, int Hdec, int K, float alpha, int accum)
{
    __shared__ __align__(16) u16 AhL[4][128][8];
    __shared__ __align__(16) u16 AlL[4][128][8];
    __shared__ __align__(16) u16 BhL[4][128][8];
    __shared__ __align__(16) u16 BlL[4][128][8];

    const int tid  = threadIdx.x;
    const int lane = tid & 63;
    const int wave = tid >> 6;
    const int quad = lane >> 4;
    const int l16  = lane & 15;
    const int z  = blockIdx.z;
    const int zp = z / (Bdec * Hdec);
    const int r  = z - zp * Bdec * Hdec;
    const int zb = r / Hdec, zh = r - zb * Hdec;
    const long long aBase = aOff + (long long)zp * aSP + (long long)zb * aSB + (long long)zh * aSH;
    const long long bBase = bOff + (long long)zp * bSP + (long long)zb * bSB + (long long)zh * bSH;
    const long long cBase = cOff + (long long)zp * cSP + (long long)zb * cSB + (long long)zh * cSH;
    const int bm = blockIdx.y * 128, bn = blockIdx.x * 128;
    const int wr = (wave >> 1) * 64, wc = (wave & 1) * 64;
    const int sm = tid >> 1;
    const int kh = (tid & 1) * 16;
    const int c0 = kh >> 3;

    const u16* gAh = Ah + aBase + (long long)(bm + sm) * lda + kh;
    const u16* gAl = Al + aBase + (long long)(bm + sm) * lda + kh;
    const u16* gBh = Bh + bBase + (long long)(bn + sm) * ldb + kh;
    const u16* gBl = Bl + bBase + (long long)(bn + sm) * ldb + kh;

    f32x4 acc[4][4];
#pragma unroll
    for (int i = 0; i < 4; i++)
#pragma unroll
        for (int j = 0; j < 4; j++) {
            acc[i][j][0] = 0.f; acc[i][j][1] = 0.f;
            acc[i][j][2] = 0.f; acc[i][j][3] = 0.f;
        }

    for (int k0 = 0; k0 < K; k0 += 32) {
        uint4 a0 = *(const uint4*)(gAh + k0);
        uint4 a1 = *(const uint4*)(gAh + k0 + 8);
        uint4 a2 = *(const uint4*)(gAl + k0);
        uint4 a3 = *(const uint4*)(gAl + k0 + 8);
        uint4 b0 = *(const uint4*)(gBh + k0);
        uint4 b1 = *(const uint4*)(gBh + k0 + 8);
        uint4 b2 = *(const uint4*)(gBl + k0);
        uint4 b3 = *(const uint4*)(gBl + k0 + 8);
        __syncthreads();
        *(uint4*)&AhL[c0][sm][0]     = a0;
        *(uint4*)&AhL[c0 + 1][sm][0] = a1;
        *(uint4*)&AlL[c0][sm][0]     = a2;
        *(uint4*)&AlL[c0 + 1][sm][0] = a3;
        *(uint4*)&BhL[c0][sm][0]     = b0;
        *(uint4*)&BhL[c0 + 1][sm][0] = b1;
        *(uint4*)&BlL[c0][sm][0]     = b2;
        *(uint4*)&BlL[c0 + 1][sm][0] = b3;
        __syncthreads();

        bf16x8 fah[4], fal[4], fbh[4], fbl[4];
#pragma unroll
        for (int i = 0; i < 4; i++) {
            fah[i] = *(const bf16x8*)&AhL[quad][wr + i * 16 + l16][0];
            fal[i] = *(const bf16x8*)&AlL[quad][wr + i * 16 + l16][0];
            fbh[i] = *(const bf16x8*)&BhL[quad][wc + i * 16 + l16][0];
            fbl[i] = *(const bf16x8*)&BlL[quad][wc + i * 16 + l16][0];
        }
#pragma unroll
        for (int i = 0; i < 4; i++)
#pragma unroll
            for (int j = 0; j < 4; j++) {
                acc[i][j] = __builtin_amdgcn_mfma_f32_16x16x32_bf16(fah[i], fbh[j], acc[i][j], 0, 0, 0);
                acc[i][j] = __builtin_amdgcn_mfma_f32_16x16x32_bf16(fah[i], fbl[j], acc[i][j], 0, 0, 0);
                acc[i][j] = __builtin_amdgcn_mfma_f32_16x16x32_bf16(fal[i], fbh[j], acc[i][j], 0, 0, 0);
            }
    }

#pragma unroll
    for (int i = 0; i < 4; i++)
#pragma unroll
        for (int j = 0; j < 4; j++)
#pragma unroll
            for (int rr = 0; rr < 4; rr++) {
                int m = bm + wr + i * 16 + quad * 4 + rr;
                int n = bn + wc + j * 16 + l16;
                long long ci = cBase + (long long)m * ldc + n;
                float c = acc[i][j][rr] * alpha;
                if (accum) c += bf16f(Ch[ci]) + bf16f(Cl[ci]);
                u16 hh = bf16_rne(c);
                Ch[ci] = hh;
                Cl[ci] = bf16_rne(c - bf16f(hh));
            }
}

// ---------------------------------------------------------------------------
// Single-bf16 GEMM (activation path). Tile 128x128x32.
// ---------------------------------------------------------------------------
__global__ __launch_bounds__(256) void gemm1(
    const u16* __restrict__ Ah,
    long long aOff, int lda, long long aSP, long long aSB, long long aSH,
    const u16* __restrict__ Bh,
    long long bOff, int ldb, long long bSP, long long bSB, long long bSH,
    u16* __restrict__ Ch, u16* __restrict__ Cl,
    long long cOff, int ldc, long long cSP, long long cSB, long long cSH,
    int Bdec, int Hdec, int K, float alpha, int accum, int storeL)
{
    __shared__ __align__(16) u16 AhL[4][128][8];
    __shared__ __align__(16) u16 BhL[4][128][8];

    const int tid  = threadIdx.x;
    const int lane = tid & 63;
    const int wave = tid >> 6;
    const int quad = lane >> 4;
    const int l16  = lane & 15;
    const int z  = blockIdx.z;
    const int zp = z / (Bdec * Hdec);
    const int r  = z - zp * Bdec * Hdec;
    const int zb = r / Hdec, zh = r - zb * Hdec;
    const long long aBase = aOff + (long long)zp * aSP + (long long)zb * aSB + (long long)zh * aSH;
    const long long bBase = bOff + (long long)zp * bSP + (long long)zb * bSB + (long long)zh * bSH;
    const long long cBase = cOff + (long long)zp * cSP + (long long)zb * cSB + (long long)zh * cSH;
    const int bm = blockIdx.y * 128, bn = blockIdx.x * 128;
    const int wr = (wave >> 1) * 64, wc = (wave & 1) * 64;
    const int sm = tid >> 1;
    const int kh = (tid & 1) * 16;
    const int c0 = kh >> 3;

    const u16* gAh = Ah + aBase + (long long)(bm + sm) * lda + kh;
    const u16* gBh = Bh + bBase + (long long)(bn + sm) * ldb + kh;

    f32x4 acc[4][4];
#pragma unroll
    for (int i = 0; i < 4; i++)
#pragma unroll
        for (int j = 0; j < 4; j++) {
            acc[i][j][0] = 0.f; acc[i][j][1] = 0.f;
            acc[i][j][2] = 0.f; acc[i][j][3] = 0.f;
        }

    for (int k0 = 0; k0 < K; k0 += 32) {
        uint4 a0 = *(const uint4*)(gAh + k0);
        uint4 a1 = *(const uint4*)(gAh + k0 + 8);
        uint4 b0 = *(const uint4*)(gBh + k0);
        uint4 b1 = *(const uint4*)(gBh + k0 + 8);
        __syncthreads();
        *(uint4*)&AhL[c0][sm][0]     = a0;
        *(uint4*)&AhL[c0 + 1][sm][0] = a1;
        *(uint4*)&BhL[c0][sm][0]     = b0;
        *(uint4*)&BhL[c0 + 1][sm][0] = b1;
        __syncthreads();

        bf16x8 fah[4], fbh[4];
#pragma unroll
        for (int i = 0; i < 4; i++) {
            fah[i] = *(const bf16x8*)&AhL[quad][wr + i * 16 + l16][0];
            fbh[i] = *(const bf16x8*)&BhL[quad][wc + i * 16 + l16][0];
        }
#pragma unroll
        for (int i = 0; i < 4; i++)
#pragma unroll
            for (int j = 0; j < 4; j++)
                acc[i][j] = __builtin_amdgcn_mfma_f32_16x16x32_bf16(fah[i], fbh[j], acc[i][j], 0, 0, 0);
    }

#pragma unroll
    for (int i = 0; i < 4; i++)
#pragma unroll
        for (int j = 0; j < 4; j++)
#pragma unroll
            for (int rr = 0; rr < 4; rr++) {
                int m = bm + wr + i * 16 + quad * 4 + rr;
                int n = bn + wc + j * 16 + l16;
                long long ci = cBase + (long long)m * ldc + n;
                float c = acc[i][j][rr] * alpha;
                if (accum) c += bf16f(Ch[ci]) + bf16f(Cl[ci]);
                u16 hh = bf16_rne(c);
                Ch[ci] = hh;
                if (storeL) Cl[ci] = bf16_rne(c - bf16f(hh));
            }
}

// ---------------------------------------------------------------------------
// Flash split-K partial: block = (q-tile 64, part, z). Part covers 256 t-cols
// (4 iterations of 64). Emits unnormalized O_p (f32) + m_p + l_p.
// ---------------------------------------------------------------------------
__global__ __launch_bounds__(256) void flash_part(
    const u16* __restrict__ Qh, const u16* __restrict__ Kh,
    const u16* __restrict__ Vth,
    float* __restrict__ Opart, float* __restrict__ Mpart, float* __restrict__ Lpart)
{
    __shared__ __align__(16) u16 Kls[64 * 136];
    __shared__ __align__(16) u16 Vls[128 * 72];
    __shared__ __align__(16) u16 pls[64 * 72];

    const int tid  = threadIdx.x;
    const int lane = tid & 63;
    const int w    = tid >> 6;
    const int quad = lane >> 4;
    const int l16  = lane & 15;
    const int z    = blockIdx.z;
    const int part = blockIdx.y;
    const int q0   = blockIdx.x * 64;
    const long long zoff = (long long)z * SDIM * DDIM;
    const int pz = part * NZ + z;

    const u16* qr = Qh + zoff + (long long)(q0 + w * 16 + l16) * DDIM;
    bf16x8 qf[4];
#pragma unroll
    for (int s = 0; s < 4; s++) qf[s] = *(const bf16x8*)(qr + s * 32 + quad * 8);

    f32x4 oacc[8];
#pragma unroll
    for (int dt = 0; dt < 8; dt++) {
        oacc[dt][0] = 0.f; oacc[dt][1] = 0.f; oacc[dt][2] = 0.f; oacc[dt][3] = 0.f;
    }
    float mold[4] = { -1e30f, -1e30f, -1e30f, -1e30f };
    float lsum[4] = { 0.f, 0.f, 0.f, 0.f };

    for (int ti = 0; ti < 4; ti++) {
        const int t0 = part * 256 + ti * 64;
        __syncthreads();
#pragma unroll
        for (int p = 0; p < 4; p++) {
            int idx = tid + p * 256;
            int t = idx >> 4, seg = (idx & 15) * 8;
            *(uint4*)&Kls[t * 136 + seg] =
                *(const uint4*)(Kh + zoff + (long long)(t0 + t) * DDIM + seg);
            int d = idx >> 3, seg2 = (idx & 7) * 8;
            *(uint4*)&Vls[d * 72 + seg2] =
                *(const uint4*)(Vth + zoff + (long long)d * SDIM + t0 + seg2);
        }
        __syncthreads();

        f32x4 sacc[4];
#pragma unroll
        for (int ct = 0; ct < 4; ct++) {
            f32x4 a; a[0] = 0.f; a[1] = 0.f; a[2] = 0.f; a[3] = 0.f;
#pragma unroll
            for (int s = 0; s < 4; s++) {
                bf16x8 kb = *(const bf16x8*)&Kls[(ct * 16 + l16) * 136 + s * 32 + quad * 8];
                a = __builtin_amdgcn_mfma_f32_16x16x32_bf16(qf[s], kb, a, 0, 0, 0);
            }
            sacc[ct] = a;
        }

        float pv[4][4], alpha[4];
#pragma unroll
        for (int r = 0; r < 4; r++) {
            float mx = -1e30f;
#pragma unroll
            for (int ct = 0; ct < 4; ct++) mx = fmaxf(mx, sacc[ct][r] * SCALE_F);
#pragma unroll
            for (int msk = 1; msk < 16; msk <<= 1) mx = fmaxf(mx, __shfl_xor(mx, msk, 64));
            float mnew = fmaxf(mold[r], mx);
            alpha[r] = expf(mold[r] - mnew);
            float rs = 0.f;
#pragma unroll
            for (int ct = 0; ct < 4; ct++) {
                float p = expf(sacc[ct][r] * SCALE_F - mnew);
                pv[ct][r] = p; rs += p;
            }
#pragma unroll
            for (int msk = 1; msk < 16; msk <<= 1) rs += __shfl_xor(rs, msk, 64);
            lsum[r] = lsum[r] * alpha[r] + rs;
            mold[r] = mnew;
        }
#pragma unroll
        for (int dt = 0; dt < 8; dt++)
#pragma unroll
            for (int r = 0; r < 4; r++) oacc[dt][r] *= alpha[r];

#pragma unroll
        for (int ct = 0; ct < 4; ct++)
#pragma unroll
            for (int r = 0; r < 4; r++)
                pls[(w * 16 + quad * 4 + r) * 72 + ct * 16 + l16] = bf16_rne(pv[ct][r]);

        bf16x8 pa[2];
#pragma unroll
        for (int ks2 = 0; ks2 < 2; ks2++)
            pa[ks2] = *(const bf16x8*)&pls[(w * 16 + l16) * 72 + ks2 * 32 + quad * 8];
#pragma unroll
        for (int dt = 0; dt < 8; dt++) {
            f32x4 o = oacc[dt];
#pragma unroll
            for (int ks2 = 0; ks2 < 2; ks2++) {
                bf16x8 vb = *(const bf16x8*)&Vls[(dt * 16 + l16) * 72 + ks2 * 32 + quad * 8];
                o = __builtin_amdgcn_mfma_f32_16x16x32_bf16(pa[ks2], vb, o, 0, 0, 0);
            }
            oacc[dt] = o;
        }
    }

    const long long obase = (long long)pz * SDIM * DDIM;
#pragma unroll
    for (int dt = 0; dt < 8; dt++)
#pragma unroll
        for (int r = 0; r < 4; r++) {
            int srow = q0 + w * 16 + quad * 4 + r;
            Opart[obase + (long long)srow * DDIM + dt * 16 + l16] = oacc[dt][r];
        }
    if (l16 == 0) {
#pragma unroll
        for (int r = 0; r < 4; r++) {
            int srow = q0 + w * 16 + quad * 4 + r;
            Mpart[(long long)pz * SDIM + srow] = mold[r];
            Lpart[(long long)pz * SDIM + srow] = lsum[r];
        }
    }
}

// ---------------------------------------------------------------------------
// Combine: O = (sum_p e^{m_p-m} O_p) / (sum_p e^{m_p-m} l_p). 2 rows/block.
// ---------------------------------------------------------------------------
__global__ __launch_bounds__(256) void flash_combine(
    const float* __restrict__ Opart, const float* __restrict__ Mpart,
    const float* __restrict__ Lpart, u16* __restrict__ Oh)
{
    const int idx = blockIdx.x * 2 + (threadIdx.x >> 7);   // (z,row): 0..16383
    const int z = idx >> 10, row = idx & 1023;
    const int d = threadIdx.x & 127;
    float mp[NPART], m = -1e30f;
#pragma unroll
    for (int p = 0; p < NPART; p++) {
        mp[p] = Mpart[(long long)(p * NZ + z) * SDIM + row];
        m = fmaxf(m, mp[p]);
    }
    float lt = 0.f, wgt[NPART];
#pragma unroll
    for (int p = 0; p < NPART; p++) {
        wgt[p] = expf(mp[p] - m);
        lt += wgt[p] * Lpart[(long long)(p * NZ + z) * SDIM + row];
    }
    float o = 0.f;
#pragma unroll
    for (int p = 0; p < NPART; p++)
        o += wgt[p] * Opart[(long long)(p * NZ + z) * SDIM * DDIM + (long long)row * DDIM + d];
    o /= lt;
    const int b = z >> 3, h = z & 7;
    Oh[(long long)b * SDIM * EDIM + (long long)row * EDIM + h * DDIM + d] = bf16_rne(o);
}

// ---------------------------------------------------------------------------
// expmap0 (h-plane): rows of 128. 4 rows/block. grid.y: 0=q,1=k.
// ---------------------------------------------------------------------------
__global__ __launch_bounds__(256) void expmap_k(
    u16* __restrict__ qh, u16* __restrict__ kh)
{
    long long row = (long long)blockIdx.x * 4 + (threadIdx.x >> 6);
    u16* h = (blockIdx.y == 0 ? qh : kh) + row * DDIM;
    const int lane = threadIdx.x & 63;
    float v0 = bf16f(h[lane]);
    float v1 = bf16f(h[lane + 64]);
    float s = v0 * v0 + v1 * v1;
#pragma unroll
    for (int off = 32; off > 0; off >>= 1) s += __shfl_down(s, off, 64);
    s = __shfl(s, 0, 64);
    float n = fmaxf(sqrtf(s), 1e-6f);
    float scl = tanhf(n) / n;
    h[lane] = bf16_rne(v0 * scl);
    h[lane + 64] = bf16_rne(v1 * scl);
}

// ---------------------------------------------------------------------------
// Generic 64x64-tile transpose. grid (rT, cT, nz).
// ---------------------------------------------------------------------------
__global__ __launch_bounds__(256) void transpose_g(
    const u16* __restrict__ src, u16* __restrict__ dst,
    int ldS, int ldD, long long sZ, long long dZ)
{
    __shared__ __align__(16) u16 tl[64][72];
    const int r0 = blockIdx.x * 64, c0 = blockIdx.y * 64;
    const u16* s = src + (long long)blockIdx.z * sZ;
    u16* d = dst + (long long)blockIdx.z * dZ;
    const int t = threadIdx.x;
    const int sr = t >> 2, dc = (t & 3) * 16;
    {
        const u16* p = s + (long long)(r0 + sr) * ldS + c0 + dc;
        *(uint4*)&tl[sr][dc]     = *(const uint4*)p;
        *(uint4*)&tl[sr][dc + 8] = *(const uint4*)(p + 8);
    }
    __syncthreads();
    const int dr = t >> 2, sc = (t & 3) * 16;
    unsigned wbuf[8];
#pragma unroll
    for (int i = 0; i < 8; i++)
        wbuf[i] = (unsigned)tl[sc + 2 * i][dr] | ((unsigned)tl[sc + 2 * i + 1][dr] << 16);
    u16* po = d + (long long)(c0 + dr) * ldD + r0 + sc;
    *(uint4*)po = make_uint4(wbuf[0], wbuf[1], wbuf[2], wbuf[3]);
    *(uint4*)(po + 8) = make_uint4(wbuf[4], wbuf[5], wbuf[6], wbuf[7]);
}

// final output: f32 = h + l (zero-fill past nmax)
__global__ __launch_bounds__(256) void out_k(
    const u16* __restrict__ h, const u16* __restrict__ l,
    float* __restrict__ out, long long n, long long nmax)
{
    long long i = (long long)blockIdx.x * 256 + threadIdx.x;
    if (i < n) out[i] = (i < nmax) ? (bf16f(h[i]) + bf16f(l[i])) : 0.f;
}

#define N2   2097152LL            // B*S*E == NZ*S*D
#define W3N  3145728LL            // 3E*E
#define WON  1048576LL            // E*E
#define WHN  49152LL              // 3*D*D
#define EE   1048576LL            // E*E

extern "C" void kernel_launch(void* const* d_in, const int* in_sizes, int n_in,
                              void* d_out, int out_size, void* d_ws, size_t ws_size,
                              hipStream_t stream)
{
    const float* x       = (const float*)d_in[0];
    const float* Wqkv    = (const float*)d_in[1];
    const float* Wq      = (const float*)d_in[3];
    const float* Wk      = (const float*)d_in[5];
    const float* Wv      = (const float*)d_in[7];
    const float* Wout    = (const float*)d_in[9];
    const float* Wlayers = (const float*)d_in[11];

    u16* ws = (u16*)d_ws;
    long long o = 0;
    u16 *curh = ws + o; o += N2;  u16 *curl = ws + o; o += N2;
    u16 *qkvh = ws + o; o += 3 * N2;
    u16 *vth  = ws + o; o += N2;
    u16 *aoh  = ws + o; o += N2;
    u16 *wqh  = ws + o; o += W3N; u16 *wql  = ws + o; o += W3N;
    u16 *wqth = ws + o; o += W3N; u16 *wqtl = ws + o; o += W3N;
    u16 *wfh  = ws + o; o += W3N; u16 *wfl  = ws + o; o += W3N;
    u16 *whh  = ws + o; o += WHN; u16 *whl  = ws + o; o += WHN;
    u16 *woh  = ws + o; o += WON; u16 *wol  = ws + o; o += WON;
    u16 *woth = ws + o; o += WON; u16 *wotl = ws + o; o += WON;
    u16 *wlh  = ws + o; o += W3N; u16 *wll  = ws + o; o += W3N;
    u16 *wloh = ws + o; o += W3N; u16 *wlol = ws + o; o += W3N;
    float *Opart = (float*)(ws + o); o += 2 * NPART * NZ * SDIM * DDIM;  // f32
    float *Mpart = (float*)(ws + o); o += 2 * NPART * NZ * SDIM;
    float *Lpart = (float*)(ws + o); o += 2 * NPART * NZ * SDIM;
    // total ~131 MB < 184 MB (R1-verified)

    // ---- one-time: splits ----
    split_k<<<2048, 256, 0, stream>>>(x, curh, curl, N2 / 4);
    split_k<<<3072, 256, 0, stream>>>(Wqkv, wqh, wql, W3N / 4);
    split_k<<<16, 256, 0, stream>>>(Wq, whh, whl, 4096);
    split_k<<<16, 256, 0, stream>>>(Wk, whh + 16384, whl + 16384, 4096);
    split_k<<<16, 256, 0, stream>>>(Wv, whh + 32768, whl + 32768, 4096);
    split_k<<<1024, 256, 0, stream>>>(Wout, woh, wol, WON / 4);
    split_k<<<3072, 256, 0, stream>>>(Wlayers, wlh, wll, W3N / 4);

    // ---- one-time: transposes ----
    transpose_g<<<dim3(48, 16, 1), 256, 0, stream>>>(wqh, wqth, EDIM, 3 * EDIM, 0, 0);
    transpose_g<<<dim3(48, 16, 1), 256, 0, stream>>>(wql, wqtl, EDIM, 3 * EDIM, 0, 0);
    transpose_g<<<dim3(16, 16, 1), 256, 0, stream>>>(woh, woth, EDIM, EDIM, 0, 0);
    transpose_g<<<dim3(16, 16, 1), 256, 0, stream>>>(wol, wotl, EDIM, EDIM, 0, 0);

    // ---- one-time: Wfused = blockdiag(Wq,Wk,Wv) @ Wqkv ----
    gemm3<<<dim3(8, 1, 24), 256, 0, stream>>>(
        whh, whl, 0, DDIM, (long long)DDIM * DDIM, 0, 0,
        wqth, wqtl, 0, 3 * EDIM, EDIM, 0, DDIM,
        wfh, wfl, 0, EDIM, (long long)EDIM * EDIM, 0, (long long)DDIM * EDIM,
        1, 8, DDIM, 1.0f, 0);

    // ---- one-time: Wlo[l] = Wlayers[l] @ Wout ----
    gemm3<<<dim3(8, 8, 3), 256, 0, stream>>>(
        wlh, wll, 0, EDIM, EE, 0, 0,
        woth, wotl, 0, EDIM, 0, 0, 0,
        wloh, wlol, 0, EDIM, EE, 0, 0,
        1, 1, EDIM, 1.0f, 0);

    for (int layer = 0; layer < LNUM; layer++) {
        // qkv fused (single-bf16): z = p*16 + b*8 + h
        gemm1<<<dim3(1, 8, 48), 256, 0, stream>>>(
            curh, 0, EDIM, 0, (long long)SDIM * EDIM, 0,
            wfh, 0, EDIM, EE, 0, (long long)DDIM * EDIM,
            qkvh, qkvh, 0, DDIM, N2, (long long)HDIM * SDIM * DDIM, (long long)SDIM * DDIM,
            2, 8, EDIM, 1.0f, 0, 0);

        // expmap0 on q,k
        expmap_k<<<dim3(NZ * SDIM / 4, 2), 256, 0, stream>>>(qkvh, qkvh + N2);

        // Vt[z][D][S] = V[z]^T
        transpose_g<<<dim3(16, 2, NZ), 256, 0, stream>>>(
            qkvh + 2 * N2, vth, DDIM, SDIM, (long long)SDIM * DDIM, (long long)SDIM * DDIM);

        // flash split-K partials + combine -> attnout (h only)
        flash_part<<<dim3(16, NPART, NZ), 256, 0, stream>>>(
            qkvh, qkvh + N2, vth, Opart, Mpart, Lpart);
        flash_combine<<<8192, 256, 0, stream>>>(Opart, Mpart, Lpart, aoh);

        // cur += attnout @ Wlo[layer]^T
        gemm1<<<dim3(8, 16, 1), 256, 0, stream>>>(
            aoh, 0, EDIM, 0, 0, 0,
            wloh, (long long)layer * EE, EDIM, 0, 0, 0,
            curh, curl, 0, EDIM, 0, 0, 0,
            1, 1, EDIM, 1.0f, 1, 1);
    }

    out_k<<<(out_size + 255) / 256, 256, 0, stream>>>(
        curh, curl, (float*)d_out, out_size, N2);
}

// Round 12
// 521.793 us; speedup vs baseline: 1.9951x; 1.1630x over previous
//
#include <hip/hip_runtime.h>
#include <math.h>

// Problem constants (reference: B=2,S=1024,E=1024,H=8,D=128,L=3)
#define BDIM 2
#define SDIM 1024
#define EDIM 1024
#define HDIM 8
#define DDIM 128
#define LNUM 3
#define NZ 16
#define NPART 4
#define SCALE_F 0.08838834764831845f
#define QSCALE_L2E 0.12751742f     // SCALE * log2(e)
#define TWO_L2E 2.8853901f         // 2 * log2(e)

// WORLD MODEL (verified R6-R11): complex64 lowered to f32 REAL-PART-ONLY.
// Precision: residual `cur` bf16x3 (h+l); everything else single bf16.
// R12: (a) no-max softmax (|logits|<=0.0884 post-expmap) + exp2 path,
// (b) weight folds via single-bf16 gemm1 (consumers only read h-plane),
// (c) expmap fused into qkv-GEMM epilogue (N-tile == D == 128).

typedef unsigned short u16;
typedef __attribute__((ext_vector_type(8))) short bf16x8;
typedef __attribute__((ext_vector_type(4))) float f32x4;

__device__ __forceinline__ u16 bf16_rne(float x) {
    unsigned u = __float_as_uint(x);
    u += 0x7FFFu + ((u >> 16) & 1u);
    return (u16)(u >> 16);
}
__device__ __forceinline__ float bf16f(u16 h) {
    return __uint_as_float(((unsigned)h) << 16);
}

// ---------------------------------------------------------------------------
__global__ __launch_bounds__(256) void split_k(
    const float* __restrict__ in, u16* __restrict__ h, u16* __restrict__ l,
    long long n4)
{
    long long i = (long long)blockIdx.x * 256 + threadIdx.x;
    if (i >= n4) return;
    float4 v = ((const float4*)in)[i];
    float vv[4] = { v.x, v.y, v.z, v.w };
    u16 hh[4], ll[4];
#pragma unroll
    for (int j = 0; j < 4; j++) {
        hh[j] = bf16_rne(vv[j]);
        ll[j] = bf16_rne(vv[j] - bf16f(hh[j]));
    }
    ((uint2*)h)[i] = make_uint2((unsigned)hh[0] | ((unsigned)hh[1] << 16),
                                (unsigned)hh[2] | ((unsigned)hh[3] << 16));
    ((uint2*)l)[i] = make_uint2((unsigned)ll[0] | ((unsigned)ll[1] << 16),
                                (unsigned)ll[2] | ((unsigned)ll[3] << 16));
}

// ---------------------------------------------------------------------------
// Single-bf16 GEMM. Tile 128x128x32, 256 thr (4 waves 2x2), 4x4 MFMA/wave.
// C[m,n] = alpha*sum_k A[m,k]*B[n,k] (+Ch+Cl if accum). storeL: write l-plane.
// doExp: if zp==0/1 (q/k slices), apply expmap0 to each output row in-epilogue
// (requires N-tile == full row == 128); q additionally scaled by QSCALE_L2E.
// ---------------------------------------------------------------------------
__global__ __launch_bounds__(256) void gemm1(
    const u16* __restrict__ Ah,
    long long aOff, int lda, long long aSP, long long aSB, long long aSH,
    const u16* __restrict__ Bh,
    long long bOff, int ldb, long long bSP, long long bSB, long long bSH,
    u16* __restrict__ Ch, u16* __restrict__ Cl,
    long long cOff, int ldc, long long cSP, long long cSB, long long cSH,
    int Bdec, int Hdec, int K, float alpha, int accum, int storeL, int doExp)
{
    __shared__ __align__(16) u16 AhL[4][128][8];
    __shared__ __align__(16) u16 BhL[4][128][8];
    __shared__ float rsum[128][2];

    const int tid  = threadIdx.x;
    const int lane = tid & 63;
    const int wave = tid >> 6;
    const int quad = lane >> 4;
    const int l16  = lane & 15;
    const int z  = blockIdx.z;
    const int zp = z / (Bdec * Hdec);
    const int r  = z - zp * Bdec * Hdec;
    const int zb = r / Hdec, zh = r - zb * Hdec;
    const long long aBase = aOff + (long long)zp * aSP + (long long)zb * aSB + (long long)zh * aSH;
    const long long bBase = bOff + (long long)zp * bSP + (long long)zb * bSB + (long long)zh * bSH;
    const long long cBase = cOff + (long long)zp * cSP + (long long)zb * cSB + (long long)zh * cSH;
    const int bm = blockIdx.y * 128, bn = blockIdx.x * 128;
    const int wr = (wave >> 1) * 64, wc = (wave & 1) * 64;
    const int sm = tid >> 1;
    const int kh = (tid & 1) * 16;
    const int c0 = kh >> 3;

    const u16* gAh = Ah + aBase + (long long)(bm + sm) * lda + kh;
    const u16* gBh = Bh + bBase + (long long)(bn + sm) * ldb + kh;

    f32x4 acc[4][4];
#pragma unroll
    for (int i = 0; i < 4; i++)
#pragma unroll
        for (int j = 0; j < 4; j++) {
            acc[i][j][0] = 0.f; acc[i][j][1] = 0.f;
            acc[i][j][2] = 0.f; acc[i][j][3] = 0.f;
        }

    for (int k0 = 0; k0 < K; k0 += 32) {
        uint4 a0 = *(const uint4*)(gAh + k0);
        uint4 a1 = *(const uint4*)(gAh + k0 + 8);
        uint4 b0 = *(const uint4*)(gBh + k0);
        uint4 b1 = *(const uint4*)(gBh + k0 + 8);
        __syncthreads();
        *(uint4*)&AhL[c0][sm][0]     = a0;
        *(uint4*)&AhL[c0 + 1][sm][0] = a1;
        *(uint4*)&BhL[c0][sm][0]     = b0;
        *(uint4*)&BhL[c0 + 1][sm][0] = b1;
        __syncthreads();

        bf16x8 fah[4], fbh[4];
#pragma unroll
        for (int i = 0; i < 4; i++) {
            fah[i] = *(const bf16x8*)&AhL[quad][wr + i * 16 + l16][0];
            fbh[i] = *(const bf16x8*)&BhL[quad][wc + i * 16 + l16][0];
        }
#pragma unroll
        for (int i = 0; i < 4; i++)
#pragma unroll
            for (int j = 0; j < 4; j++)
                acc[i][j] = __builtin_amdgcn_mfma_f32_16x16x32_bf16(fah[i], fbh[j], acc[i][j], 0, 0, 0);
    }

    // ---- optional fused expmap0 (q/k slices of the qkv projection) ----
    if (doExp && zp < 2) {
        const float qs = (zp == 0) ? QSCALE_L2E : 1.0f;
#pragma unroll
        for (int i = 0; i < 4; i++)
#pragma unroll
            for (int rr = 0; rr < 4; rr++) {
                float ps = 0.f;
#pragma unroll
                for (int j = 0; j < 4; j++) {
                    float v = acc[i][j][rr];
                    ps += v * v;
                }
                ps += __shfl_xor(ps, 1, 64); ps += __shfl_xor(ps, 2, 64);
                ps += __shfl_xor(ps, 4, 64); ps += __shfl_xor(ps, 8, 64);
                if (l16 == 0) rsum[wr + i * 16 + quad * 4 + rr][wc >> 6] = ps;
            }
        __syncthreads();
#pragma unroll
        for (int i = 0; i < 4; i++)
#pragma unroll
            for (int rr = 0; rr < 4; rr++) {
                int m = wr + i * 16 + quad * 4 + rr;
                float n2 = rsum[m][0] + rsum[m][1];
                float nn = fmaxf(sqrtf(n2), 1e-6f);
                float e2 = exp2f(TWO_L2E * nn);          // e^{2n}
                float scl = (1.f - 2.f / (e2 + 1.f)) / nn * qs;  // tanh(n)/n * qs
#pragma unroll
                for (int j = 0; j < 4; j++) acc[i][j][rr] *= scl;
            }
    }

#pragma unroll
    for (int i = 0; i < 4; i++)
#pragma unroll
        for (int j = 0; j < 4; j++)
#pragma unroll
            for (int rr = 0; rr < 4; rr++) {
                int m = bm + wr + i * 16 + quad * 4 + rr;
                int n = bn + wc + j * 16 + l16;
                long long ci = cBase + (long long)m * ldc + n;
                float c = acc[i][j][rr] * alpha;
                if (accum) c += bf16f(Ch[ci]) + bf16f(Cl[ci]);
                u16 hh = bf16_rne(c);
                Ch[ci] = hh;
                if (storeL) Cl[ci] = bf16_rne(c - bf16f(hh));
            }
}

// ---------------------------------------------------------------------------
// Flash split-K partial, no-max softmax (bounded logits; Q pre-scaled by
// SCALE*log2e so P = exp2(sacc)). Emits unnormalized O_p (f32) + l_p.
// ---------------------------------------------------------------------------
__global__ __launch_bounds__(256) void flash_part(
    const u16* __restrict__ Qh, const u16* __restrict__ Kh,
    const u16* __restrict__ Vth,
    float* __restrict__ Opart, float* __restrict__ Lpart)
{
    __shared__ __align__(16) u16 Kls[64 * 136];
    __shared__ __align__(16) u16 Vls[128 * 72];
    __shared__ __align__(16) u16 pls[64 * 72];

    const int tid  = threadIdx.x;
    const int lane = tid & 63;
    const int w    = tid >> 6;
    const int quad = lane >> 4;
    const int l16  = lane & 15;
    const int z    = blockIdx.z;
    const int part = blockIdx.y;
    const int q0   = blockIdx.x * 64;
    const long long zoff = (long long)z * SDIM * DDIM;
    const int pz = part * NZ + z;

    const u16* qr = Qh + zoff + (long long)(q0 + w * 16 + l16) * DDIM;
    bf16x8 qf[4];
#pragma unroll
    for (int s = 0; s < 4; s++) qf[s] = *(const bf16x8*)(qr + s * 32 + quad * 8);

    f32x4 oacc[8];
#pragma unroll
    for (int dt = 0; dt < 8; dt++) {
        oacc[dt][0] = 0.f; oacc[dt][1] = 0.f; oacc[dt][2] = 0.f; oacc[dt][3] = 0.f;
    }
    float lp[4] = { 0.f, 0.f, 0.f, 0.f };

    for (int ti = 0; ti < 4; ti++) {
        const int t0 = part * 256 + ti * 64;
        __syncthreads();
#pragma unroll
        for (int p = 0; p < 4; p++) {
            int idx = tid + p * 256;
            int t = idx >> 4, seg = (idx & 15) * 8;
            *(uint4*)&Kls[t * 136 + seg] =
                *(const uint4*)(Kh + zoff + (long long)(t0 + t) * DDIM + seg);
            int d = idx >> 3, seg2 = (idx & 7) * 8;
            *(uint4*)&Vls[d * 72 + seg2] =
                *(const uint4*)(Vth + zoff + (long long)d * SDIM + t0 + seg2);
        }
        __syncthreads();

        f32x4 sacc[4];
#pragma unroll
        for (int ct = 0; ct < 4; ct++) {
            f32x4 a; a[0] = 0.f; a[1] = 0.f; a[2] = 0.f; a[3] = 0.f;
#pragma unroll
            for (int s = 0; s < 4; s++) {
                bf16x8 kb = *(const bf16x8*)&Kls[(ct * 16 + l16) * 136 + s * 32 + quad * 8];
                a = __builtin_amdgcn_mfma_f32_16x16x32_bf16(qf[s], kb, a, 0, 0, 0);
            }
            sacc[ct] = a;
        }

        // P = exp2(sacc); accumulate per-thread row partials (no max needed)
#pragma unroll
        for (int ct = 0; ct < 4; ct++)
#pragma unroll
            for (int r = 0; r < 4; r++) {
                float p = exp2f(sacc[ct][r]);
                lp[r] += p;
                pls[(w * 16 + quad * 4 + r) * 72 + ct * 16 + l16] = bf16_rne(p);
            }

        bf16x8 pa[2];
#pragma unroll
        for (int ks2 = 0; ks2 < 2; ks2++)
            pa[ks2] = *(const bf16x8*)&pls[(w * 16 + l16) * 72 + ks2 * 32 + quad * 8];
#pragma unroll
        for (int dt = 0; dt < 8; dt++) {
            f32x4 o = oacc[dt];
#pragma unroll
            for (int ks2 = 0; ks2 < 2; ks2++) {
                bf16x8 vb = *(const bf16x8*)&Vls[(dt * 16 + l16) * 72 + ks2 * 32 + quad * 8];
                o = __builtin_amdgcn_mfma_f32_16x16x32_bf16(pa[ks2], vb, o, 0, 0, 0);
            }
            oacc[dt] = o;
        }
    }

    const long long obase = (long long)pz * SDIM * DDIM;
#pragma unroll
    for (int dt = 0; dt < 8; dt++)
#pragma unroll
        for (int r = 0; r < 4; r++) {
            int srow = q0 + w * 16 + quad * 4 + r;
            Opart[obase + (long long)srow * DDIM + dt * 16 + l16] = oacc[dt][r];
        }
#pragma unroll
    for (int r = 0; r < 4; r++) {
        float s = lp[r];
        s += __shfl_xor(s, 1, 64); s += __shfl_xor(s, 2, 64);
        s += __shfl_xor(s, 4, 64); s += __shfl_xor(s, 8, 64);
        if (l16 == 0) {
            int srow = q0 + w * 16 + quad * 4 + r;
            Lpart[(long long)pz * SDIM + srow] = s;
        }
    }
}

// ---------------------------------------------------------------------------
// Combine: O = sum_p O_p / sum_p l_p. 2 (z,row) pairs per 256-thr block.
// ---------------------------------------------------------------------------
__global__ __launch_bounds__(256) void flash_combine(
    const float* __restrict__ Opart, const float* __restrict__ Lpart,
    u16* __restrict__ Oh)
{
    const int idx = blockIdx.x * 2 + (threadIdx.x >> 7);   // 0..16383
    const int z = idx >> 10, row = idx & 1023;
    const int d = threadIdx.x & 127;
    float lt = 0.f;
#pragma unroll
    for (int p = 0; p < NPART; p++)
        lt += Lpart[(long long)(p * NZ + z) * SDIM + row];
    float o = 0.f;
#pragma unroll
    for (int p = 0; p < NPART; p++)
        o += Opart[(long long)(p * NZ + z) * SDIM * DDIM + (long long)row * DDIM + d];
    o /= lt;
    const int b = z >> 3, h = z & 7;
    Oh[(long long)b * SDIM * EDIM + (long long)row * EDIM + h * DDIM + d] = bf16_rne(o);
}

// ---------------------------------------------------------------------------
// Generic 64x64-tile transpose. grid (rT, cT, nz).
// ---------------------------------------------------------------------------
__global__ __launch_bounds__(256) void transpose_g(
    const u16* __restrict__ src, u16* __restrict__ dst,
    int ldS, int ldD, long long sZ, long long dZ)
{
    __shared__ __align__(16) u16 tl[64][72];
    const int r0 = blockIdx.x * 64, c0 = blockIdx.y * 64;
    const u16* s = src + (long long)blockIdx.z * sZ;
    u16* d = dst + (long long)blockIdx.z * dZ;
    const int t = threadIdx.x;
    const int sr = t >> 2, dc = (t & 3) * 16;
    {
        const u16* p = s + (long long)(r0 + sr) * ldS + c0 + dc;
        *(uint4*)&tl[sr][dc]     = *(const uint4*)p;
        *(uint4*)&tl[sr][dc + 8] = *(const uint4*)(p + 8);
    }
    __syncthreads();
    const int dr = t >> 2, sc = (t & 3) * 16;
    unsigned wbuf[8];
#pragma unroll
    for (int i = 0; i < 8; i++)
        wbuf[i] = (unsigned)tl[sc + 2 * i][dr] | ((unsigned)tl[sc + 2 * i + 1][dr] << 16);
    u16* po = d + (long long)(c0 + dr) * ldD + r0 + sc;
    *(uint4*)po = make_uint4(wbuf[0], wbuf[1], wbuf[2], wbuf[3]);
    *(uint4*)(po + 8) = make_uint4(wbuf[4], wbuf[5], wbuf[6], wbuf[7]);
}

// final output: f32 = h + l (zero-fill past nmax)
__global__ __launch_bounds__(256) void out_k(
    const u16* __restrict__ h, const u16* __restrict__ l,
    float* __restrict__ out, long long n, long long nmax)
{
    long long i = (long long)blockIdx.x * 256 + threadIdx.x;
    if (i < n) out[i] = (i < nmax) ? (bf16f(h[i]) + bf16f(l[i])) : 0.f;
}

#define N2   2097152LL            // B*S*E == NZ*S*D
#define W3N  3145728LL            // 3E*E
#define WON  1048576LL            // E*E
#define WHN  49152LL              // 3*D*D
#define EE   1048576LL            // E*E

extern "C" void kernel_launch(void* const* d_in, const int* in_sizes, int n_in,
                              void* d_out, int out_size, void* d_ws, size_t ws_size,
                              hipStream_t stream)
{
    const float* x       = (const float*)d_in[0];
    const float* Wqkv    = (const float*)d_in[1];
    const float* Wq      = (const float*)d_in[3];
    const float* Wk      = (const float*)d_in[5];
    const float* Wv      = (const float*)d_in[7];
    const float* Wout    = (const float*)d_in[9];
    const float* Wlayers = (const float*)d_in[11];

    u16* ws = (u16*)d_ws;
    long long o = 0;
    u16 *curh = ws + o; o += N2;  u16 *curl = ws + o; o += N2;
    u16 *qkvh = ws + o; o += 3 * N2;
    u16 *vth  = ws + o; o += N2;
    u16 *aoh  = ws + o; o += N2;
    u16 *wqh  = ws + o; o += W3N;
    u16 *wqth = ws + o; o += W3N;
    u16 *wfh  = ws + o; o += W3N;
    u16 *whh  = ws + o; o += WHN;
    u16 *woh  = ws + o; o += WON;
    u16 *woth = ws + o; o += WON;
    u16 *wlh  = ws + o; o += W3N;
    u16 *wloh = ws + o; o += W3N;
    u16 *ltrash = ws + o; o += W3N;     // dummy l-plane for weight splits
    float *Opart = (float*)(ws + o); o += 2 * NPART * NZ * SDIM * DDIM;  // f32
    float *Lpart = (float*)(ws + o); o += 2 * NPART * NZ * SDIM;
    // total ~108 MB < 184 MB (R1-verified)

    // ---- one-time: splits (weights: l-plane discarded) ----
    split_k<<<2048, 256, 0, stream>>>(x, curh, curl, N2 / 4);
    split_k<<<3072, 256, 0, stream>>>(Wqkv, wqh, ltrash, W3N / 4);
    split_k<<<16, 256, 0, stream>>>(Wq, whh, ltrash, 4096);
    split_k<<<16, 256, 0, stream>>>(Wk, whh + 16384, ltrash, 4096);
    split_k<<<16, 256, 0, stream>>>(Wv, whh + 32768, ltrash, 4096);
    split_k<<<1024, 256, 0, stream>>>(Wout, woh, ltrash, WON / 4);
    split_k<<<3072, 256, 0, stream>>>(Wlayers, wlh, ltrash, W3N / 4);

    // ---- one-time: transposes (h-planes only) ----
    transpose_g<<<dim3(48, 16, 1), 256, 0, stream>>>(wqh, wqth, EDIM, 3 * EDIM, 0, 0);
    transpose_g<<<dim3(16, 16, 1), 256, 0, stream>>>(woh, woth, EDIM, EDIM, 0, 0);

    // ---- one-time: Wfused = blockdiag(Wq,Wk,Wv) @ Wqkv  (single-bf16) ----
    gemm1<<<dim3(8, 1, 24), 256, 0, stream>>>(
        whh, 0, DDIM, (long long)DDIM * DDIM, 0, 0,
        wqth, 0, 3 * EDIM, EDIM, 0, DDIM,
        wfh, wfh, 0, EDIM, (long long)EDIM * EDIM, 0, (long long)DDIM * EDIM,
        1, 8, DDIM, 1.0f, 0, 0, 0);

    // ---- one-time: Wlo[l] = Wlayers[l] @ Wout  (single-bf16) ----
    gemm1<<<dim3(8, 8, 3), 256, 0, stream>>>(
        wlh, 0, EDIM, EE, 0, 0,
        woth, 0, EDIM, 0, 0, 0,
        wloh, wloh, 0, EDIM, EE, 0, 0,
        1, 1, EDIM, 1.0f, 0, 0, 0);

    for (int layer = 0; layer < LNUM; layer++) {
        // qkv fused + epilogue expmap (q scaled by SCALE*log2e):
        // z = p*16 + b*8 + h: M=1024(s), N=128(d), K=1024
        gemm1<<<dim3(1, 8, 48), 256, 0, stream>>>(
            curh, 0, EDIM, 0, (long long)SDIM * EDIM, 0,
            wfh, 0, EDIM, EE, 0, (long long)DDIM * EDIM,
            qkvh, qkvh, 0, DDIM, N2, (long long)HDIM * SDIM * DDIM, (long long)SDIM * DDIM,
            2, 8, EDIM, 1.0f, 0, 0, 1);

        // Vt[z][D][S] = V[z]^T
        transpose_g<<<dim3(16, 2, NZ), 256, 0, stream>>>(
            qkvh + 2 * N2, vth, DDIM, SDIM, (long long)SDIM * DDIM, (long long)SDIM * DDIM);

        // flash split-K partials + combine -> attnout (h only)
        flash_part<<<dim3(16, NPART, NZ), 256, 0, stream>>>(
            qkvh, qkvh + N2, vth, Opart, Lpart);
        flash_combine<<<8192, 256, 0, stream>>>(Opart, Lpart, aoh);

        // cur += attnout @ Wlo[layer]^T
        gemm1<<<dim3(8, 16, 1), 256, 0, stream>>>(
            aoh, 0, EDIM, 0, 0, 0,
            wloh, (long long)layer * EE, EDIM, 0, 0, 0,
            curh, curl, 0, EDIM, 0, 0, 0,
            1, 1, EDIM, 1.0f, 1, 1, 0);
    }

    out_k<<<(out_size + 255) / 256, 256, 0, stream>>>(
        curh, curl, (float*)d_out, out_size, N2);
}